// Round 4
// baseline (489.834 us; speedup 1.0000x reference)
//
#include <hip/hip_runtime.h>
#include <cstdint>
#include <cstddef>

typedef unsigned short u16;
typedef __attribute__((ext_vector_type(4))) short short4v;
typedef __attribute__((ext_vector_type(8))) short short8;
typedef __attribute__((ext_vector_type(4))) float f32x4;

__device__ __forceinline__ float bf2f(u16 h) { return __uint_as_float(((unsigned)h) << 16); }
__device__ __forceinline__ u16 f2bf(float f) {
    unsigned u = __float_as_uint(f);
    unsigned r = (u + 0x7fffu + ((u >> 16) & 1u)) >> 16;
    return (u16)r;
}
// round-half-up: <=0.5 ULP, 2 VALU ops (flash inner loop)
__device__ __forceinline__ u16 f2bf_fast(float f) {
    return (u16)((__float_as_uint(f) + 0x8000u) >> 16);
}

__device__ __forceinline__ void gl_lds16(const void* g, void* l) {
    __builtin_amdgcn_global_load_lds((const __attribute__((address_space(1))) void*)g,
                                     (__attribute__((address_space(3))) void*)l, 16, 0, 0);
}

// ---------------- dtype detection: flag=1 if inputs are bf16, 0 if f32 ------
__global__ __launch_bounds__(256) void detect_kernel(const unsigned* __restrict__ x,
                                                     int* __restrict__ flag) {
    __shared__ int cnt[256];
    int c = 0;
    for (int i = threadIdx.x; i < 4096; i += 256) {
        unsigned lo = x[i] & 0xFFFFu;
        unsigned e = (lo >> 7) & 0xFFu;
        c += (e >= 100u && e <= 150u) ? 1 : 0;
    }
    cnt[threadIdx.x] = c;
    __syncthreads();
    for (int s = 128; s > 0; s >>= 1) {
        if (threadIdx.x < s) cnt[threadIdx.x] += cnt[threadIdx.x + s];
        __syncthreads();
    }
    if (threadIdx.x == 0) *flag = (cnt[0] > 2048) ? 1 : 0;
}

// ---------------- param convert (biases/gamma/beta) -> f32 pool -------------
struct ParamCvt {
    const void* src[12];
    int off[12];
    int n[12];
};
__global__ __launch_bounds__(256) void param_cvt_kernel(ParamCvt pc, float* __restrict__ dst,
                                                        const int* __restrict__ flag) {
    const int bf = *flag;
    const int s = blockIdx.x;
    const void* sp = pc.src[s];
    float* dp = dst + pc.off[s];
    const int n = pc.n[s];
    for (int i = threadIdx.x; i < n; i += 256)
        dp[i] = bf ? bf2f(((const u16*)sp)[i]) : ((const float*)sp)[i];
}

// ---------------- x -> bf16 (4 elems/thread) --------------------------------
__global__ __launch_bounds__(256) void cvt_x_kernel(const void* __restrict__ x,
                                                    u16* __restrict__ xb,
                                                    const int* __restrict__ flag) {
    const int bf = *flag;
    const int i0 = (blockIdx.x * 256 + threadIdx.x) * 4;
    u16 o[4];
    if (bf) {
        *(uint2*)o = *(const uint2*)((const u16*)x + i0);
    } else {
        float4 f = *(const float4*)((const float*)x + i0);
        o[0] = f2bf(f.x); o[1] = f2bf(f.y); o[2] = f2bf(f.z); o[3] = f2bf(f.w);
    }
    *(uint2*)&xb[i0] = *(uint2*)o;
}

// ---------------- fused transpose+cast of all 8 weights ---------------------
struct TAll {
    const void* src[8];
    u16* dst[8];
    int R[8], C[8];
    int off[8];
};
__global__ __launch_bounds__(256) void transpose_all_kernel(TAll t,
                                                            const int* __restrict__ flag) {
    const int bf = *flag;
    __shared__ u16 tile[32][33];
    int bid = blockIdx.x;
    int m = 0;
#pragma unroll
    for (int i = 1; i < 8; i++) m = (bid >= t.off[i]) ? i : m;
    int local = bid - t.off[m];
    const int R = t.R[m], C = t.C[m];
    const int tilesx = C >> 5;
    const int bx = local % tilesx, by = local / tilesx;
    const void* src = t.src[m];
    u16* dst = t.dst[m];
    const int tx = threadIdx.x & 31, ty = threadIdx.x >> 5;   // ty 0..7
#pragma unroll
    for (int i = 0; i < 32; i += 8) {
        size_t idx = (size_t)(by * 32 + ty + i) * C + bx * 32 + tx;
        tile[ty + i][tx] = bf ? ((const u16*)src)[idx] : f2bf(((const float*)src)[idx]);
    }
    __syncthreads();
#pragma unroll
    for (int i = 0; i < 32; i += 8)
        dst[(size_t)(bx * 32 + ty + i) * R + by * 32 + tx] = tile[tx][ty + i];
}

// ---------------- LayerNorm over C=1024 (bf16 in, f32 params, bf16 out) -----
__global__ __launch_bounds__(256) void ln_kernel(const u16* __restrict__ X,
                                                 const float* __restrict__ G,
                                                 const float* __restrict__ Be,
                                                 u16* __restrict__ Y) {
    const int row = blockIdx.x;
    const int tid = threadIdx.x;
    const int lane = tid & 63, wave = tid >> 6;
    const u16* xr = X + (size_t)row * 1024;
    u16 vbuf[4];
    *(uint2*)vbuf = *(const uint2*)&xr[tid * 4];
    float f[4];
    float s = 0.f, sq = 0.f;
#pragma unroll
    for (int j = 0; j < 4; j++) { f[j] = bf2f(vbuf[j]); s += f[j]; sq += f[j] * f[j]; }
#pragma unroll
    for (int m = 1; m < 64; m <<= 1) { s += __shfl_xor(s, m, 64); sq += __shfl_xor(sq, m, 64); }
    __shared__ float rs_[4], rq_[4];
    if (lane == 0) { rs_[wave] = s; rq_[wave] = sq; }
    __syncthreads();
    float S = rs_[0] + rs_[1] + rs_[2] + rs_[3];
    float Q2 = rq_[0] + rq_[1] + rq_[2] + rq_[3];
    float mean = S * (1.f / 1024.f);
    float var = Q2 * (1.f / 1024.f) - mean * mean;
    float rstd = rsqrtf(var + 1e-5f);
    u16 o[4];
#pragma unroll
    for (int j = 0; j < 4; j++) {
        int c2 = tid * 4 + j;
        float y = (f[j] - mean) * rstd * G[c2] + Be[c2];
        o[j] = f2bf(y);
    }
    *(uint2*)&Y[(size_t)row * 1024 + tid * 4] = *(uint2*)o;
}

// ---------------- GEMM 128x128 (legacy path, small shapes) ------------------
// out(MxN) = A(MxK) @ Bt(NxK)^T + bias (+res1+res2); split-K via gridDim.z.
template <int TAG>
__global__ __launch_bounds__(256) void gemm_bt_kernel(const u16* __restrict__ A,
                                                      const u16* __restrict__ Bt,
                                                      const float* __restrict__ bias,
                                                      const u16* __restrict__ res1,
                                                      const u16* __restrict__ res2,
                                                      void* __restrict__ out,
                                                      void* __restrict__ out_k,
                                                      void* __restrict__ out_v,
                                                      int M, int N, int K, int relu, int mode,
                                                      const int* __restrict__ flag) {
    __shared__ __align__(16) u16 As[2][128 * 32];
    __shared__ __align__(16) u16 Bs[2][128 * 32];
    const int tid = threadIdx.x;
    const int wave = tid >> 6, lane = tid & 63;
    const int m0 = blockIdx.y * 128, n0 = blockIdx.x * 128;
    const int wm = (wave >> 1) * 64, wn = (wave & 1) * 64;

    f32x4 acc[4][4];
#pragma unroll
    for (int i = 0; i < 4; i++)
#pragma unroll
        for (int j = 0; j < 4; j++) acc[i][j] = (f32x4){0.f, 0.f, 0.f, 0.f};

    const int lr4 = lane >> 2;                         // 0..15 (row in 16-row chunk)
    const int sc4 = ((lane & 3) ^ ((lane >> 3) & 3));  // swizzled source col-chunk

    const int Ksub = K / (int)gridDim.z;
    const int kbeg = blockIdx.z * Ksub;

    auto stage = [&](int k0, int bufi) {
#pragma unroll
        for (int c = 0; c < 2; c++) {
            int rbase = wave * 32 + c * 16;
            int arow = m0 + rbase + lr4;
            int brow = n0 + rbase + lr4;
            if (brow > N - 1) brow = N - 1;
            gl_lds16(A + (size_t)arow * K + k0 + sc4 * 8, &As[bufi][rbase * 32 + lane * 8]);
            gl_lds16(Bt + (size_t)brow * K + k0 + sc4 * 8, &Bs[bufi][rbase * 32 + lane * 8]);
        }
    };

    stage(kbeg, 0);
    __syncthreads();
    const int nk = Ksub >> 5;
    for (int ik = 0; ik < nk; ik++) {
        const int cur = ik & 1;
        if (ik + 1 < nk) stage(kbeg + ((ik + 1) << 5), cur ^ 1);
        short8 af[4], bf[4];
        const int cc = (lane >> 4) ^ ((lane >> 1) & 3);  // swizzled read chunk
#pragma unroll
        for (int i = 0; i < 4; i++)
            af[i] = *(const short8*)&As[cur][(wm + i * 16 + (lane & 15)) * 32 + cc * 8];
#pragma unroll
        for (int j = 0; j < 4; j++)
            bf[j] = *(const short8*)&Bs[cur][(wn + j * 16 + (lane & 15)) * 32 + cc * 8];
#pragma unroll
        for (int i = 0; i < 4; i++)
#pragma unroll
            for (int j = 0; j < 4; j++)
                acc[i][j] = __builtin_amdgcn_mfma_f32_16x16x32_bf16(af[i], bf[j], acc[i][j], 0, 0, 0);
        __syncthreads();
    }

    // epilogue: C/D layout col=lane&15, row=(lane>>4)*4+r  (m89-verified)
    if (mode == 3) {
        float* po = (float*)out + (size_t)blockIdx.z * M * N;
#pragma unroll
        for (int j = 0; j < 4; j++) {
            int col = n0 + wn + j * 16 + (lane & 15);
            if (col >= N) continue;
#pragma unroll
            for (int i = 0; i < 4; i++)
#pragma unroll
                for (int r = 0; r < 4; r++) {
                    int row = m0 + wm + i * 16 + (lane >> 4) * 4 + r;
                    po[(size_t)row * N + col] = acc[i][j][r];
                }
        }
        return;
    }

    const int f32out = (mode == 1) && (*flag == 0);
#pragma unroll
    for (int j = 0; j < 4; j++) {
        int col = n0 + wn + j * 16 + (lane & 15);
        if (col >= N) continue;
        float bv = bias ? bias[col] : 0.f;
#pragma unroll
        for (int i = 0; i < 4; i++) {
#pragma unroll
            for (int r = 0; r < 4; r++) {
                int row = m0 + wm + i * 16 + (lane >> 4) * 4 + r;
                float v = acc[i][j][r] + bv;
                if (relu) v = fmaxf(v, 0.f);
                size_t idx = (size_t)row * N + col;
                if (res1) v += bf2f(res1[idx]);
                if (res2) v += bf2f(res2[idx]);
                if (f32out) ((float*)out)[idx] = v;
                else ((u16*)out)[idx] = f2bf(v);
            }
        }
    }
}

// ---------------- GEMM 256x256, K-region deep pipeline (T2+T3+T4+T5) --------
// BK=64, 8 waves (2Mx4N). LDS regions are K-MAJOR: As[buf][kh] = rows 0..255
// x k-half kh (32 wide), 16 KB each. Phase order per tile: (mh,kh) =
// (0,0),(1,0),(0,1),(1,1) -- so k0 regions are dead after ph1 (lgkmcnt(0)+
// barrier sealed), k1 after ph3. Stage calendar (race-free by construction):
//   t.ph0: (t+1,A.k1)  t.ph1: (t+1,B.k1)  t.ph2: (t+2,A.k0)  t.ph3: (t+2,B.k0)
// Counted waits (2 loads/region): end-ph1 vmcnt(8) covers (t,k1); end-ph3
// vmcnt(8) covers (t+1,k0); exact tail reductions. Never vmcnt(0) in steady
// state. Swizzle involution phys_chunk = logical ^ ((row>>1)&3) applied to
// BOTH the global source and the ds_read (rule #21); per-16-lane beat hits
// all 8 bank groups at 2 lanes/group. Requires M%256==0, N%256==0, nt>=2.
template <int TAG>
__global__ __launch_bounds__(512, 2) void gemm256_kernel(const u16* __restrict__ A,
                                                         const u16* __restrict__ Bt,
                                                         const float* __restrict__ bias,
                                                         const u16* __restrict__ res1,
                                                         const u16* __restrict__ res2,
                                                         void* __restrict__ out,
                                                         void* __restrict__ out_k,
                                                         void* __restrict__ out_v,
                                                         int M, int N, int K, int relu, int mode,
                                                         const int* __restrict__ flag) {
    (void)flag; (void)M;
    __shared__ __align__(16) u16 As[2][2][256 * 32];   // [buf][kh][row*32+chunk*8]
    __shared__ __align__(16) u16 Bs[2][2][256 * 32];
    const int tid = threadIdx.x;
    const int wave = tid >> 6, lane = tid & 63;
    const int l15 = lane & 15, quad = lane >> 4;
    const int wr = wave >> 2, wc = wave & 3;           // 2x4 wave grid
    const int m0 = blockIdx.y * 256, n0 = blockIdx.x * 256;

    const int Ksub = K / (int)gridDim.z;
    const int kbeg = blockIdx.z * Ksub;
    const int nt = Ksub >> 6;

    // staging: wave covers rows [wave*16,+16) and [128+wave*16,+16) of a region;
    // lane l -> phys row l>>2, phys chunk l&3; source logical chunk pre-swizzled
    const int rsub = lane >> 2;                        // 0..15
    const int logc = (lane & 3) ^ ((rsub >> 1) & 3);   // involution f(r)=(r>>1)&3

    auto stage_region = [&](int t, int kh, int isB) {
        const int buf = t & 1;
        const int kk = kbeg + (t << 6) + (kh << 5) + logc * 8;
        u16* dst = (isB ? &Bs[buf][kh][0] : &As[buf][kh][0]) + wave * 512 + lane * 8;
        const u16* sp = isB ? Bt : A;
        const int r0 = (isB ? n0 : m0) + wave * 16 + rsub;
        gl_lds16(sp + (size_t)r0 * K + kk, dst);
        gl_lds16(sp + (size_t)(r0 + 128) * K + kk, dst + 4096);
    };

    f32x4 acc[8][4];
#pragma unroll
    for (int i = 0; i < 8; i++)
#pragma unroll
        for (int j = 0; j < 4; j++) acc[i][j] = (f32x4){0.f, 0.f, 0.f, 0.f};

    // prologue: (0,k0)A,B ; (0,k1)A,B ; (1,k0)A,B ; wait tile0.k0 complete
    stage_region(0, 0, 0); stage_region(0, 0, 1);
    stage_region(0, 1, 0); stage_region(0, 1, 1);
    if (nt > 1) {
        stage_region(1, 0, 0); stage_region(1, 0, 1);
        asm volatile("s_waitcnt vmcnt(8)" ::: "memory");
    } else {
        asm volatile("s_waitcnt vmcnt(4)" ::: "memory");
    }
    __builtin_amdgcn_s_barrier();

    const int rx = (l15 >> 1) & 3;                     // read-side involution
    for (int t = 0; t < nt; t++) {
        const int b = t & 1;
        short8 bfr[4];
#pragma unroll
        for (int ph = 0; ph < 4; ph++) {
            const int mh = ph & 1, kh = ph >> 1;
            short8 af[4];
#pragma unroll
            for (int i = 0; i < 4; i++)
                af[i] = *(const short8*)&As[b][kh][(wr * 128 + mh * 64 + i * 16 + l15) * 32 +
                                                   ((quad ^ rx) << 3)];
            if (mh == 0) {
#pragma unroll
                for (int j = 0; j < 4; j++)
                    bfr[j] = *(const short8*)&Bs[b][kh][(wc * 64 + j * 16 + l15) * 32 +
                                                        ((quad ^ rx) << 3)];
            }
            // stage calendar (targets sealed-dead regions only)
            if (ph == 0)      { if (t + 1 < nt) stage_region(t + 1, 1, 0); }
            else if (ph == 1) { if (t + 1 < nt) stage_region(t + 1, 1, 1); }
            else if (ph == 2) { if (t + 2 < nt) stage_region(t + 2, 0, 0); }
            else              { if (t + 2 < nt) stage_region(t + 2, 0, 1); }
            __builtin_amdgcn_s_barrier();
            asm volatile("s_waitcnt lgkmcnt(0)" ::: "memory");
            __builtin_amdgcn_s_setprio(1);
#pragma unroll
            for (int i = 0; i < 4; i++)
#pragma unroll
                for (int j = 0; j < 4; j++)
                    acc[mh * 4 + i][j] = __builtin_amdgcn_mfma_f32_16x16x32_bf16(
                        af[i], bfr[j], acc[mh * 4 + i][j], 0, 0, 0);
            __builtin_amdgcn_s_setprio(0);
            if (ph == 1) {
                if (t + 1 < nt) { asm volatile("s_waitcnt vmcnt(8)" ::: "memory"); }
                else            { asm volatile("s_waitcnt vmcnt(0)" ::: "memory"); }
            } else if (ph == 3) {
                if (t + 2 < nt)      { asm volatile("s_waitcnt vmcnt(8)" ::: "memory"); }
                else if (t + 1 < nt) { asm volatile("s_waitcnt vmcnt(4)" ::: "memory"); }
            }
            __builtin_amdgcn_s_barrier();
        }
    }

    // epilogue: C/D layout col=lane&15, row=quad*4+r (m89-verified)
    if (mode == 3) {
        float* po = (float*)out + (size_t)blockIdx.z * M * N;
#pragma unroll
        for (int j = 0; j < 4; j++) {
            const int col = n0 + wc * 64 + j * 16 + l15;
#pragma unroll
            for (int ig = 0; ig < 8; ig++) {
                const int row0 = m0 + wr * 128 + ig * 16 + quad * 4;
#pragma unroll
                for (int r = 0; r < 4; r++)
                    po[(size_t)(row0 + r) * N + col] = acc[ig][j][r];
            }
        }
        return;
    }
    if (mode == 2) {
        const int region = n0 >> 10;
        if (region < 2) {
            u16* o = (u16*)(region == 0 ? out : out_k);
#pragma unroll
            for (int j = 0; j < 4; j++) {
                const int col = n0 + wc * 64 + j * 16 + l15;
                const float bv = bias[col];
                const int cl = col & 1023;
#pragma unroll
                for (int ig = 0; ig < 8; ig++) {
                    const int row0 = m0 + wr * 128 + ig * 16 + quad * 4;
#pragma unroll
                    for (int r = 0; r < 4; r++)
                        o[(size_t)(row0 + r) * 1024 + cl] = f2bf(acc[ig][j][r] + bv);
                }
            }
        } else {
            u16* o = (u16*)out_v;
#pragma unroll
            for (int j = 0; j < 4; j++) {
                const int col = n0 + wc * 64 + j * 16 + l15;
                const float bv = bias[col];
                const int cl = col & 1023;
                const int h = cl >> 6, d = cl & 63;
#pragma unroll
                for (int ig = 0; ig < 8; ig++) {
                    const int row_base = m0 + wr * 128 + ig * 16 + quad * 4;
                    const int bb = row_base >> 11, tt = row_base & 2047;
                    u16 pk[4];
#pragma unroll
                    for (int r = 0; r < 4; r++) pk[r] = f2bf(acc[ig][j][r] + bv);
                    *(uint2*)&o[(((size_t)bb * 16 + h) * 64 + d) * 2048 + tt] = *(uint2*)pk;
                }
            }
        }
        return;
    }
    // mode 0: bias [+relu] [+res] -> bf16
#pragma unroll
    for (int j = 0; j < 4; j++) {
        const int col = n0 + wc * 64 + j * 16 + l15;
        const float bv = bias ? bias[col] : 0.f;
#pragma unroll
        for (int ig = 0; ig < 8; ig++) {
            const int row0 = m0 + wr * 128 + ig * 16 + quad * 4;
#pragma unroll
            for (int r = 0; r < 4; r++) {
                float v = acc[ig][j][r] + bv;
                if (relu) v = fmaxf(v, 0.f);
                const size_t idx = (size_t)(row0 + r) * N + col;
                if (res1) v += bf2f(res1[idx]);
                if (res2) v += bf2f(res2[idx]);
                ((u16*)out)[idx] = f2bf(v);
            }
        }
    }
}

// ---------------- split-K reduce: out = f(sum_z part[z]) --------------------
template <int TAG>
__global__ __launch_bounds__(256) void reduce_kernel(const float* __restrict__ part,
                                                     int nsplit, size_t MN,
                                                     const float* __restrict__ bias, int N,
                                                     const u16* __restrict__ res1,
                                                     const u16* __restrict__ res2,
                                                     void* __restrict__ out,
                                                     int relu, int final_store,
                                                     const int* __restrict__ flag) {
    const size_t i0 = ((size_t)blockIdx.x * 256 + threadIdx.x) * 4;
    float4 s = *(const float4*)&part[i0];
    for (int z = 1; z < nsplit; z++) {
        float4 p = *(const float4*)&part[(size_t)z * MN + i0];
        s.x += p.x; s.y += p.y; s.z += p.z; s.w += p.w;
    }
    const int col = (int)(i0 & (size_t)(N - 1));
    float v[4] = {s.x, s.y, s.z, s.w};
#pragma unroll
    for (int j = 0; j < 4; j++) {
        v[j] += bias[col + j];
        if (relu) v[j] = fmaxf(v[j], 0.f);
    }
    if (res1) {
        u16 r[4]; *(uint2*)r = *(const uint2*)&res1[i0];
#pragma unroll
        for (int j = 0; j < 4; j++) v[j] += bf2f(r[j]);
    }
    if (res2) {
        u16 r[4]; *(uint2*)r = *(const uint2*)&res2[i0];
#pragma unroll
        for (int j = 0; j < 4; j++) v[j] += bf2f(r[j]);
    }
    if (final_store && (*flag == 0)) {
        *(float4*)&((float*)out)[i0] = (float4){v[0], v[1], v[2], v[3]};
    } else {
        u16 o[4];
#pragma unroll
        for (int j = 0; j < 4; j++) o[j] = f2bf(v[j]);
        *(uint2*)&((u16*)out)[i0] = *(uint2*)o;
    }
}

// ---------------- flash attention v6: 64-query tile, 4 waves ----------------
// One 16-row q-group per wave; grid (32,32)=1024 blocks of 256 threads so
// 4-5 blocks (16-20 waves) fit per CU and causal imbalance backfills at 2x
// finer granularity. With 64-row tiles every resident wave is active at every
// K-step (no masked-idle waves). S^T = mfma(kf, qf) keeps scores in the
// A-fragment layout of 16x16x16 MFMA so P feeds PV straight from registers.
__global__ __launch_bounds__(256) void flash_kernel(const u16* __restrict__ Q,
                                                    const u16* __restrict__ Kg,
                                                    const u16* __restrict__ VtG,
                                                    u16* __restrict__ O) {
    const int tid = threadIdx.x;
    const int wave = tid >> 6, lane = tid & 63;
    const int qb = 31 - blockIdx.x;            // reversed: long blocks first
    const int bh = blockIdx.y;
    const int t0 = qb * 64;
    const size_t base = ((size_t)(bh >> 4) * 2048) * 1024 + (size_t)(bh & 15) * 64;
    const size_t basev = (size_t)bh * 64 * 2048;

    __shared__ __align__(16) u16 Ks[2][64 * 64];
    __shared__ __align__(16) u16 Vt[2][64 * 64];
#if !__has_builtin(__builtin_amdgcn_mfma_f32_16x16x16bf16_1k)
    __shared__ __align__(16) u16 Ps[4][16 * 72];
#endif

    const int l15 = lane & 15, quad = lane >> 4;
    const int rmin = t0 + wave * 16;           // this wave's 16 q-rows

    // Q fragments (B-operand): lane holds Q[qrow=l15][d = st*32 + quad*8 ..+7]
    short8 qf[2];
    {
        const u16* qp = Q + base + (size_t)(rmin + l15) * 1024 + quad * 8;
        qf[0] = *(const short8*)qp;
        qf[1] = *(const short8*)(qp + 32);
    }

    const int slr = lane >> 3;                 // 0..7
    const int sc8 = (lane & 7) ^ slr;          // swizzled source col-chunk
    const int rb = wave * 16;                  // 4 waves x 16 rows = 64-row tile

    auto stage = [&](int kt, int bufi) {
        gl_lds16(Kg + base + (size_t)(kt * 64 + rb + slr) * 1024 + sc8 * 8,
                 &Ks[bufi][rb * 64 + lane * 8]);
        gl_lds16(Kg + base + (size_t)(kt * 64 + rb + 8 + slr) * 1024 + sc8 * 8,
                 &Ks[bufi][(rb + 8) * 64 + lane * 8]);
        gl_lds16(VtG + basev + (size_t)(rb + slr) * 2048 + kt * 64 + sc8 * 8,
                 &Vt[bufi][rb * 64 + lane * 8]);
        gl_lds16(VtG + basev + (size_t)(rb + 8 + slr) * 2048 + kt * 64 + sc8 * 8,
                 &Vt[bufi][(rb + 8) * 64 + lane * 8]);
    };

    float l_part = 0.f;
    f32x4 oacc[4];
#pragma unroll
    for (int jt = 0; jt < 4; jt++) oacc[jt] = (f32x4){0.f, 0.f, 0.f, 0.f};

    const float Cs = 0.125f * 1.44269504f;     // scale * log2(e)
    const int ktmax = qb;

    stage(0, 0);
    __syncthreads();

    for (int kt = 0; kt <= ktmax; kt++) {
        const int cur = kt & 1;
        if (kt < ktmax) stage(kt + 1, cur ^ 1);   // prefetch overlaps compute

        // K fragments (A-operand): lane holds K[key=j*16+l15][d chunk st*4+quad]
        short8 kf[2][4];
#pragma unroll
        for (int st = 0; st < 2; st++)
#pragma unroll
            for (int j = 0; j < 4; j++)
                kf[st][j] = *(const short8*)&Ks[cur][(j * 16 + l15) * 64 +
                                                     (((st * 4 + quad) ^ (l15 & 7)) * 8)];
#if __has_builtin(__builtin_amdgcn_mfma_f32_16x16x16bf16_1k)
        // V b64 fragments for 16x16x16 PV: lane holds V[key=j*16+quad*4+jj][d=jt*16+l15]
        short4v vf[4][4];
#pragma unroll
        for (int j = 0; j < 4; j++) {
            int k8 = j * 2 + (quad >> 1);      // data key-chunk
#pragma unroll
            for (int jt = 0; jt < 4; jt++) {
                int d = jt * 16 + l15;
                vf[j][jt] = *(const short4v*)&Vt[cur][d * 64 + ((k8 ^ (d & 7)) * 8) +
                                                      (quad & 1) * 4];
            }
        }
#else
        short8 vf[2][4];
#pragma unroll
        for (int st = 0; st < 2; st++)
#pragma unroll
            for (int jt = 0; jt < 4; jt++) {
                int d = jt * 16 + l15;
                vf[st][jt] = *(const short8*)&Vt[cur][d * 64 + (((st * 4 + quad) ^ (d & 7)) * 8)];
            }
#endif

        // S^T = K Q^T : lane gets qrow=l15, keys j*16+quad*4+r
        f32x4 s[4];
#pragma unroll
        for (int j = 0; j < 4; j++) s[j] = (f32x4){0.f, 0.f, 0.f, 0.f};
#pragma unroll
        for (int st = 0; st < 2; st++)
#pragma unroll
            for (int j = 0; j < 4; j++)
                s[j] = __builtin_amdgcn_mfma_f32_16x16x32_bf16(kf[st][j], qf[st], s[j], 0, 0, 0);

        const int qrow = rmin + l15;
        const bool needmask = (kt * 64 + 63 > rmin);
        float lp = l_part;
        short4v pj[4];
#pragma unroll
        for (int j = 0; j < 4; j++) {
            union { short4v v; u16 u[4]; } pk;
#pragma unroll
            for (int r = 0; r < 4; r++) {
                float p = __builtin_amdgcn_exp2f(s[j][r] * Cs);
                int key = kt * 64 + j * 16 + quad * 4 + r;
                if (needmask && key > qrow) p = 0.f;
                lp += p;
                pk.u[r] = f2bf_fast(p);
            }
            pj[j] = pk.v;
        }
        l_part = lp;

#if __has_builtin(__builtin_amdgcn_mfma_f32_16x16x16bf16_1k)
        // O += P V, P straight from registers (A-frag match)
#pragma unroll
        for (int jt = 0; jt < 4; jt++)
#pragma unroll
            for (int j = 0; j < 4; j++)
                oacc[jt] = __builtin_amdgcn_mfma_f32_16x16x16bf16_1k(pj[j], vf[j][jt],
                                                                     oacc[jt], 0, 0, 0);
#else
        // fallback: b64 P-writes to padded LDS, b128 reads as 16x16x32 A-frag
        u16* Pw = Ps[wave];
#pragma unroll
        for (int j = 0; j < 4; j++)
            *(short4v*)&Pw[l15 * 72 + j * 16 + quad * 4] = pj[j];
#pragma unroll
        for (int st = 0; st < 2; st++) {
            short8 pf = *(const short8*)&Pw[l15 * 72 + st * 32 + quad * 8];
#pragma unroll
            for (int jt = 0; jt < 4; jt++)
                oacc[jt] = __builtin_amdgcn_mfma_f32_16x16x32_bf16(pf, vf[st][jt],
                                                                  oacc[jt], 0, 0, 0);
        }
#endif
        __syncthreads();
    }

    // finalize: l lives per qrow=l15; reduce across quads, broadcast to C-rows
    {
        float lf = l_part;
        lf += __shfl_xor(lf, 16, 64);
        lf += __shfl_xor(lf, 32, 64);
        float inv[4];
#pragma unroll
        for (int r = 0; r < 4; r++) inv[r] = 1.f / __shfl(lf, quad * 4 + r, 64);
#pragma unroll
        for (int jt = 0; jt < 4; jt++) {
            int d = jt * 16 + l15;
#pragma unroll
            for (int r = 0; r < 4; r++) {
                int t = rmin + quad * 4 + r;
                O[base + (size_t)t * 1024 + d] = f2bf(oacc[jt][r] * inv[r]);
            }
        }
    }
}

extern "C" void kernel_launch(void* const* d_in, const int* in_sizes, int n_in,
                              void* d_out, int out_size, void* d_ws, size_t ws_size,
                              hipStream_t stream) {
    (void)in_sizes; (void)n_in; (void)out_size;
    const void* x   = d_in[0];
    // d_in[1] = attn_mask (int32, pure causal) -- implemented directly
    const void* Wq  = d_in[2];  const void* bq  = d_in[3];
    const void* Wk  = d_in[4];  const void* bk  = d_in[5];
    const void* Wv  = d_in[6];  const void* bv  = d_in[7];
    const void* Wo  = d_in[8];  const void* bo  = d_in[9];
    const void* g1  = d_in[10]; const void* be1 = d_in[11];
    const void* g2  = d_in[12]; const void* be2 = d_in[13];
    const void* W1  = d_in[14]; const void* bf1 = d_in[15];
    const void* W2  = d_in[16]; const void* bf2 = d_in[17];
    const void* Wd  = d_in[18]; const void* bd  = d_in[19];
    const void* Wu  = d_in[20]; const void* bu  = d_in[21];

    uint8_t* w8 = (uint8_t*)d_ws;
    int* flag = (int*)w8;                    // 64 B header
    float* pf = (float*)(w8 + 64);           // f32 param pool
    u16* wsb = (u16*)(w8 + 64 + 65536);      // bf16 arena

    const size_t M1 = 1024ull * 1024ull;
    u16* WqT = wsb;                          // Wq/Wk/Wv transposed, contiguous 3072xK
    u16* WkT = wsb + 1 * M1;
    u16* WvT = wsb + 2 * M1;
    u16* WoT = wsb + 3 * M1;
    u16* W1T = wsb + 4 * M1;                 // 4M
    u16* W2T = wsb + 8 * M1;                 // 4M
    u16* WdT = wsb + 12 * M1;                // 64K
    u16* WuT = wsb + 12 * M1 + 65536;        // 64K
    u16* S0  = wsb + 12 * M1 + 131072;
    u16* Areg = S0;                          // xb
    u16* Breg = S0 + 4 * M1;                 // xn -> attn
    u16* ff1  = S0;                          // 16M spans Areg+Breg+8M fresh
    u16* Creg = S0 + 16 * M1;                // q -> xn2 -> bot
    u16* Dreg = S0 + 20 * M1;                // k -> x1
    u16* Ereg = S0 + 24 * M1;                // VtG -> hh
    u16* xb = Areg;
    u16* xn = Breg; u16* attn = Breg;
    u16* q = Creg;  u16* xn2 = Creg;  u16* bot = Creg;
    u16* kk_ = Dreg; u16* x1 = Dreg;
    u16* VtG = Ereg; u16* hh = Ereg;

    // split-K partial buffer: 64 MB f32 after the bf16 arena
    const size_t arena_bytes = (size_t)(64 + 65536) + (40 * M1 + 131072) * 2;
    float* partf = (float*)(w8 + ((arena_bytes + 255) & ~(size_t)255));
    const size_t need = ((arena_bytes + 255) & ~(size_t)255) + 4ull * 4 * M1 * 4;  // Z=4 x 4M f32
    const bool sk = ws_size >= need;

    float* bqkv_f = pf + 0;    // bq,bk,bv contiguous (3072)
    float* bo_f  = pf + 3072;
    float* bf1_f = pf + 4096;  float* bf2_f = pf + 8192;
    float* bd_f  = pf + 9216;  float* bu_f  = pf + 9280;
    float* g1_f  = pf + 10304; float* be1_f = pf + 11328;
    float* g2_f  = pf + 12352; float* be2_f = pf + 13376;

    detect_kernel<<<1, 256, 0, stream>>>((const unsigned*)x, flag);

    ParamCvt pc;
    const void* srcs[12] = {bq, bk, bv, bo, bf1, bf2, bd, bu, g1, be1, g2, be2};
    int offs[12] = {0, 1024, 2048, 3072, 4096, 8192, 9216, 9280, 10304, 11328, 12352, 13376};
    int ns[12]   = {1024, 1024, 1024, 1024, 4096, 1024, 64, 1024, 1024, 1024, 1024, 1024};
    for (int i = 0; i < 12; i++) { pc.src[i] = srcs[i]; pc.off[i] = offs[i]; pc.n[i] = ns[i]; }
    param_cvt_kernel<<<12, 256, 0, stream>>>(pc, pf, flag);

    cvt_x_kernel<<<4096, 256, 0, stream>>>(x, xb, flag);

    TAll ta;
    const void* tsrc[8] = {Wq, Wk, Wv, Wo, W1, W2, Wd, Wu};
    u16* tdst[8] = {WqT, WkT, WvT, WoT, W1T, W2T, WdT, WuT};
    int tR[8] = {1024, 1024, 1024, 1024, 1024, 4096, 1024, 64};
    int tC[8] = {1024, 1024, 1024, 1024, 4096, 1024, 64, 1024};
    int acc_off = 0;
    for (int i = 0; i < 8; i++) {
        ta.src[i] = tsrc[i]; ta.dst[i] = tdst[i];
        ta.R[i] = tR[i]; ta.C[i] = tC[i];
        ta.off[i] = acc_off;
        acc_off += (tR[i] >> 5) * (tC[i] >> 5);
    }
    transpose_all_kernel<<<acc_off, 256, 0, stream>>>(ta, flag);

    ln_kernel<<<4096, 256, 0, stream>>>(xb, g1_f, be1_f, xn);
    // TAG 0: fused QKV (N=3072, V written transposed per-head into VtG), 256^2 pipeline
    gemm256_kernel<0><<<dim3(12, 16), 512, 0, stream>>>(xn, WqT, bqkv_f, nullptr, nullptr,
                                                        q, kk_, VtG, 4096, 3072, 1024, 0, 2, flag);
    flash_kernel<<<dim3(32, 32), 256, 0, stream>>>(q, kk_, VtG, attn);
    // TAG 1: Wo projection + residual (split-K 4, 256^2 pipeline, nt=4)
    if (sk) {
        gemm256_kernel<1><<<dim3(4, 16, 4), 512, 0, stream>>>(attn, WoT, nullptr, nullptr, nullptr,
                                                              partf, nullptr, nullptr, 4096, 1024, 1024, 0, 3, flag);
        reduce_kernel<1><<<4096, 256, 0, stream>>>(partf, 4, 4 * M1, bo_f, 1024, xb, nullptr,
                                                   x1, 0, 0, flag);
    } else {
        gemm_bt_kernel<1><<<dim3(8, 32), 256, 0, stream>>>(attn, WoT, bo_f, xb, nullptr,
                                                           x1, nullptr, nullptr, 4096, 1024, 1024, 0, 0, flag);
    }
    ln_kernel<<<4096, 256, 0, stream>>>(x1, g2_f, be2_f, xn2);
    // TAG 2: FFN1 (relu), 256^2 pipeline
    gemm256_kernel<2><<<dim3(16, 16), 512, 0, stream>>>(xn2, W1T, bf1_f, nullptr, nullptr,
                                                        ff1, nullptr, nullptr, 4096, 4096, 1024, 1, 0, flag);
    // TAG 3: FFN2 (split-K 4, 256^2 pipeline, nt=16)
    if (sk) {
        gemm256_kernel<3><<<dim3(4, 16, 4), 512, 0, stream>>>(ff1, W2T, nullptr, nullptr, nullptr,
                                                              partf, nullptr, nullptr, 4096, 1024, 4096, 0, 3, flag);
        reduce_kernel<3><<<4096, 256, 0, stream>>>(partf, 4, 4 * M1, bf2_f, 1024, nullptr, nullptr,
                                                   hh, 0, 0, flag);
    } else {
        gemm_bt_kernel<3><<<dim3(8, 32), 256, 0, stream>>>(ff1, W2T, bf2_f, nullptr, nullptr,
                                                           hh, nullptr, nullptr, 4096, 1024, 4096, 0, 0, flag);
    }
    // TAG 4: adapter down (relu, split-K 8) -- N=64, stays on 128^2 kernel
    if (sk) {
        gemm_bt_kernel<4><<<dim3(1, 32, 8), 256, 0, stream>>>(hh, WdT, nullptr, nullptr, nullptr,
                                                              partf, nullptr, nullptr, 4096, 64, 1024, 1, 3, flag);
        reduce_kernel<4><<<256, 256, 0, stream>>>(partf, 8, 256 * 1024, bd_f, 64, nullptr, nullptr,
                                                  bot, 1, 0, flag);
    } else {
        gemm_bt_kernel<4><<<dim3(1, 32), 256, 0, stream>>>(hh, WdT, bd_f, nullptr, nullptr,
                                                           bot, nullptr, nullptr, 4096, 64, 1024, 1, 0, flag);
    }
    // TAG 5: adapter up + residuals (final store) -- K=64, stays on 128^2 kernel
    gemm_bt_kernel<5><<<dim3(8, 32), 256, 0, stream>>>(bot, WuT, bu_f, hh, x1,
                                                       d_out, nullptr, nullptr, 4096, 1024, 64, 0, 1, flag);
}

// Round 5
// 481.355 us; speedup vs baseline: 1.0176x; 1.0176x over previous
//
#include <hip/hip_runtime.h>
#include <cstdint>
#include <cstddef>

typedef unsigned short u16;
typedef __attribute__((ext_vector_type(4))) short short4v;
typedef __attribute__((ext_vector_type(8))) short short8;
typedef __attribute__((ext_vector_type(4))) float f32x4;

__device__ __forceinline__ float bf2f(u16 h) { return __uint_as_float(((unsigned)h) << 16); }
__device__ __forceinline__ u16 f2bf(float f) {
    unsigned u = __float_as_uint(f);
    unsigned r = (u + 0x7fffu + ((u >> 16) & 1u)) >> 16;
    return (u16)r;
}
// round-half-up: <=0.5 ULP, 2 VALU ops (flash inner loop)
__device__ __forceinline__ u16 f2bf_fast(float f) {
    return (u16)((__float_as_uint(f) + 0x8000u) >> 16);
}

__device__ __forceinline__ void gl_lds16(const void* g, void* l) {
    __builtin_amdgcn_global_load_lds((const __attribute__((address_space(1))) void*)g,
                                     (__attribute__((address_space(3))) void*)l, 16, 0, 0);
}

// ---------------- dtype detection: flag=1 if inputs are bf16, 0 if f32 ------
__global__ __launch_bounds__(256) void detect_kernel(const unsigned* __restrict__ x,
                                                     int* __restrict__ flag) {
    __shared__ int cnt[256];
    int c = 0;
    for (int i = threadIdx.x; i < 4096; i += 256) {
        unsigned lo = x[i] & 0xFFFFu;
        unsigned e = (lo >> 7) & 0xFFu;
        c += (e >= 100u && e <= 150u) ? 1 : 0;
    }
    cnt[threadIdx.x] = c;
    __syncthreads();
    for (int s = 128; s > 0; s >>= 1) {
        if (threadIdx.x < s) cnt[threadIdx.x] += cnt[threadIdx.x + s];
        __syncthreads();
    }
    if (threadIdx.x == 0) *flag = (cnt[0] > 2048) ? 1 : 0;
}

// ---------------- param convert (biases/gamma/beta) -> f32 pool -------------
struct ParamCvt {
    const void* src[12];
    int off[12];
    int n[12];
};
__global__ __launch_bounds__(256) void param_cvt_kernel(ParamCvt pc, float* __restrict__ dst,
                                                        const int* __restrict__ flag) {
    const int bf = *flag;
    const int s = blockIdx.x;
    const void* sp = pc.src[s];
    float* dp = dst + pc.off[s];
    const int n = pc.n[s];
    for (int i = threadIdx.x; i < n; i += 256)
        dp[i] = bf ? bf2f(((const u16*)sp)[i]) : ((const float*)sp)[i];
}

// ---------------- x -> bf16 (4 elems/thread) --------------------------------
__global__ __launch_bounds__(256) void cvt_x_kernel(const void* __restrict__ x,
                                                    u16* __restrict__ xb,
                                                    const int* __restrict__ flag) {
    const int bf = *flag;
    const int i0 = (blockIdx.x * 256 + threadIdx.x) * 4;
    u16 o[4];
    if (bf) {
        *(uint2*)o = *(const uint2*)((const u16*)x + i0);
    } else {
        float4 f = *(const float4*)((const float*)x + i0);
        o[0] = f2bf(f.x); o[1] = f2bf(f.y); o[2] = f2bf(f.z); o[3] = f2bf(f.w);
    }
    *(uint2*)&xb[i0] = *(uint2*)o;
}

// ---------------- fused transpose+cast of all 8 weights ---------------------
struct TAll {
    const void* src[8];
    u16* dst[8];
    int R[8], C[8];
    int off[8];
};
__global__ __launch_bounds__(256) void transpose_all_kernel(TAll t,
                                                            const int* __restrict__ flag) {
    const int bf = *flag;
    __shared__ u16 tile[32][33];
    int bid = blockIdx.x;
    int m = 0;
#pragma unroll
    for (int i = 1; i < 8; i++) m = (bid >= t.off[i]) ? i : m;
    int local = bid - t.off[m];
    const int R = t.R[m], C = t.C[m];
    const int tilesx = C >> 5;
    const int bx = local % tilesx, by = local / tilesx;
    const void* src = t.src[m];
    u16* dst = t.dst[m];
    const int tx = threadIdx.x & 31, ty = threadIdx.x >> 5;   // ty 0..7
#pragma unroll
    for (int i = 0; i < 32; i += 8) {
        size_t idx = (size_t)(by * 32 + ty + i) * C + bx * 32 + tx;
        tile[ty + i][tx] = bf ? ((const u16*)src)[idx] : f2bf(((const float*)src)[idx]);
    }
    __syncthreads();
#pragma unroll
    for (int i = 0; i < 32; i += 8)
        dst[(size_t)(bx * 32 + ty + i) * R + by * 32 + tx] = tile[tx][ty + i];
}

// ---------------- LayerNorm over C=1024 (bf16 in, f32 params, bf16 out) -----
__global__ __launch_bounds__(256) void ln_kernel(const u16* __restrict__ X,
                                                 const float* __restrict__ G,
                                                 const float* __restrict__ Be,
                                                 u16* __restrict__ Y) {
    const int row = blockIdx.x;
    const int tid = threadIdx.x;
    const int lane = tid & 63, wave = tid >> 6;
    const u16* xr = X + (size_t)row * 1024;
    u16 vbuf[4];
    *(uint2*)vbuf = *(const uint2*)&xr[tid * 4];
    float f[4];
    float s = 0.f, sq = 0.f;
#pragma unroll
    for (int j = 0; j < 4; j++) { f[j] = bf2f(vbuf[j]); s += f[j]; sq += f[j] * f[j]; }
#pragma unroll
    for (int m = 1; m < 64; m <<= 1) { s += __shfl_xor(s, m, 64); sq += __shfl_xor(sq, m, 64); }
    __shared__ float rs_[4], rq_[4];
    if (lane == 0) { rs_[wave] = s; rq_[wave] = sq; }
    __syncthreads();
    float S = rs_[0] + rs_[1] + rs_[2] + rs_[3];
    float Q2 = rq_[0] + rq_[1] + rq_[2] + rq_[3];
    float mean = S * (1.f / 1024.f);
    float var = Q2 * (1.f / 1024.f) - mean * mean;
    float rstd = rsqrtf(var + 1e-5f);
    u16 o[4];
#pragma unroll
    for (int j = 0; j < 4; j++) {
        int c2 = tid * 4 + j;
        float y = (f[j] - mean) * rstd * G[c2] + Be[c2];
        o[j] = f2bf(y);
    }
    *(uint2*)&Y[(size_t)row * 1024 + tid * 4] = *(uint2*)o;
}

// ---------------- GEMM 128x128 (legacy path, small shapes) ------------------
// out(MxN) = A(MxK) @ Bt(NxK)^T + bias (+res1+res2); split-K via gridDim.z.
template <int TAG>
__global__ __launch_bounds__(256) void gemm_bt_kernel(const u16* __restrict__ A,
                                                      const u16* __restrict__ Bt,
                                                      const float* __restrict__ bias,
                                                      const u16* __restrict__ res1,
                                                      const u16* __restrict__ res2,
                                                      void* __restrict__ out,
                                                      void* __restrict__ out_k,
                                                      void* __restrict__ out_v,
                                                      int M, int N, int K, int relu, int mode,
                                                      const int* __restrict__ flag) {
    __shared__ __align__(16) u16 As[2][128 * 32];
    __shared__ __align__(16) u16 Bs[2][128 * 32];
    const int tid = threadIdx.x;
    const int wave = tid >> 6, lane = tid & 63;
    const int m0 = blockIdx.y * 128, n0 = blockIdx.x * 128;
    const int wm = (wave >> 1) * 64, wn = (wave & 1) * 64;

    f32x4 acc[4][4];
#pragma unroll
    for (int i = 0; i < 4; i++)
#pragma unroll
        for (int j = 0; j < 4; j++) acc[i][j] = (f32x4){0.f, 0.f, 0.f, 0.f};

    const int lr4 = lane >> 2;                         // 0..15 (row in 16-row chunk)
    const int sc4 = ((lane & 3) ^ ((lane >> 3) & 3));  // swizzled source col-chunk

    const int Ksub = K / (int)gridDim.z;
    const int kbeg = blockIdx.z * Ksub;

    auto stage = [&](int k0, int bufi) {
#pragma unroll
        for (int c = 0; c < 2; c++) {
            int rbase = wave * 32 + c * 16;
            int arow = m0 + rbase + lr4;
            int brow = n0 + rbase + lr4;
            if (brow > N - 1) brow = N - 1;
            gl_lds16(A + (size_t)arow * K + k0 + sc4 * 8, &As[bufi][rbase * 32 + lane * 8]);
            gl_lds16(Bt + (size_t)brow * K + k0 + sc4 * 8, &Bs[bufi][rbase * 32 + lane * 8]);
        }
    };

    stage(kbeg, 0);
    __syncthreads();
    const int nk = Ksub >> 5;
    for (int ik = 0; ik < nk; ik++) {
        const int cur = ik & 1;
        if (ik + 1 < nk) stage(kbeg + ((ik + 1) << 5), cur ^ 1);
        short8 af[4], bf[4];
        const int cc = (lane >> 4) ^ ((lane >> 1) & 3);  // swizzled read chunk
#pragma unroll
        for (int i = 0; i < 4; i++)
            af[i] = *(const short8*)&As[cur][(wm + i * 16 + (lane & 15)) * 32 + cc * 8];
#pragma unroll
        for (int j = 0; j < 4; j++)
            bf[j] = *(const short8*)&Bs[cur][(wn + j * 16 + (lane & 15)) * 32 + cc * 8];
#pragma unroll
        for (int i = 0; i < 4; i++)
#pragma unroll
            for (int j = 0; j < 4; j++)
                acc[i][j] = __builtin_amdgcn_mfma_f32_16x16x32_bf16(af[i], bf[j], acc[i][j], 0, 0, 0);
        __syncthreads();
    }

    // epilogue: C/D layout col=lane&15, row=(lane>>4)*4+r  (m89-verified)
    if (mode == 3) {
        float* po = (float*)out + (size_t)blockIdx.z * M * N;
#pragma unroll
        for (int j = 0; j < 4; j++) {
            int col = n0 + wn + j * 16 + (lane & 15);
            if (col >= N) continue;
#pragma unroll
            for (int i = 0; i < 4; i++)
#pragma unroll
                for (int r = 0; r < 4; r++) {
                    int row = m0 + wm + i * 16 + (lane >> 4) * 4 + r;
                    po[(size_t)row * N + col] = acc[i][j][r];
                }
        }
        return;
    }

    const int f32out = (mode == 1) && (*flag == 0);
#pragma unroll
    for (int j = 0; j < 4; j++) {
        int col = n0 + wn + j * 16 + (lane & 15);
        if (col >= N) continue;
        float bv = bias ? bias[col] : 0.f;
#pragma unroll
        for (int i = 0; i < 4; i++) {
#pragma unroll
            for (int r = 0; r < 4; r++) {
                int row = m0 + wm + i * 16 + (lane >> 4) * 4 + r;
                float v = acc[i][j][r] + bv;
                if (relu) v = fmaxf(v, 0.f);
                size_t idx = (size_t)row * N + col;
                if (res1) v += bf2f(res1[idx]);
                if (res2) v += bf2f(res2[idx]);
                if (f32out) ((float*)out)[idx] = v;
                else ((u16*)out)[idx] = f2bf(v);
            }
        }
    }
}

// ---------------- GEMM 256x256, K-region deep pipeline (T2+T3+T4+T5) --------
// BK=64, 8 waves (2Mx4N). LDS regions are K-MAJOR: As[buf][kh] = rows 0..255
// x k-half kh (32 wide), 16 KB each. Phase order per tile: (mh,kh) =
// (0,0),(1,0),(0,1),(1,1) -- so k0 regions are dead after ph1 (lgkmcnt(0)+
// barrier sealed), k1 after ph3. Stage calendar (race-free by construction):
//   t.ph0: (t+1,A.k1)  t.ph1: (t+1,B.k1)  t.ph2: (t+2,A.k0)  t.ph3: (t+2,B.k0)
// Counted waits (2 loads/region): end-ph1 vmcnt(8) covers (t,k1); end-ph3
// vmcnt(8) covers (t+1,k0); exact tail reductions. Never vmcnt(0) in steady
// state. Swizzle involution phys_chunk = logical ^ ((row>>1)&3) applied to
// BOTH the global source and the ds_read (rule #21); per-16-lane beat hits
// all 8 bank groups at 2 lanes/group. Requires M%256==0, N%256==0, nt>=2.
template <int TAG>
__global__ __launch_bounds__(512, 2) void gemm256_kernel(const u16* __restrict__ A,
                                                         const u16* __restrict__ Bt,
                                                         const float* __restrict__ bias,
                                                         const u16* __restrict__ res1,
                                                         const u16* __restrict__ res2,
                                                         void* __restrict__ out,
                                                         void* __restrict__ out_k,
                                                         void* __restrict__ out_v,
                                                         int M, int N, int K, int relu, int mode,
                                                         const int* __restrict__ flag) {
    (void)flag; (void)M;
    __shared__ __align__(16) u16 As[2][2][256 * 32];   // [buf][kh][row*32+chunk*8]
    __shared__ __align__(16) u16 Bs[2][2][256 * 32];
    const int tid = threadIdx.x;
    const int wave = tid >> 6, lane = tid & 63;
    const int l15 = lane & 15, quad = lane >> 4;
    const int wr = wave >> 2, wc = wave & 3;           // 2x4 wave grid
    const int m0 = blockIdx.y * 256, n0 = blockIdx.x * 256;

    const int Ksub = K / (int)gridDim.z;
    const int kbeg = blockIdx.z * Ksub;
    const int nt = Ksub >> 6;

    // staging: wave covers rows [wave*16,+16) and [128+wave*16,+16) of a region;
    // lane l -> phys row l>>2, phys chunk l&3; source logical chunk pre-swizzled
    const int rsub = lane >> 2;                        // 0..15
    const int logc = (lane & 3) ^ ((rsub >> 1) & 3);   // involution f(r)=(r>>1)&3

    auto stage_region = [&](int t, int kh, int isB) {
        const int buf = t & 1;
        const int kk = kbeg + (t << 6) + (kh << 5) + logc * 8;
        u16* dst = (isB ? &Bs[buf][kh][0] : &As[buf][kh][0]) + wave * 512 + lane * 8;
        const u16* sp = isB ? Bt : A;
        const int r0 = (isB ? n0 : m0) + wave * 16 + rsub;
        gl_lds16(sp + (size_t)r0 * K + kk, dst);
        gl_lds16(sp + (size_t)(r0 + 128) * K + kk, dst + 4096);
    };

    f32x4 acc[8][4];
#pragma unroll
    for (int i = 0; i < 8; i++)
#pragma unroll
        for (int j = 0; j < 4; j++) acc[i][j] = (f32x4){0.f, 0.f, 0.f, 0.f};

    // prologue: (0,k0)A,B ; (0,k1)A,B ; (1,k0)A,B ; wait tile0.k0 complete
    stage_region(0, 0, 0); stage_region(0, 0, 1);
    stage_region(0, 1, 0); stage_region(0, 1, 1);
    if (nt > 1) {
        stage_region(1, 0, 0); stage_region(1, 0, 1);
        asm volatile("s_waitcnt vmcnt(8)" ::: "memory");
    } else {
        asm volatile("s_waitcnt vmcnt(4)" ::: "memory");
    }
    __builtin_amdgcn_s_barrier();

    const int rx = (l15 >> 1) & 3;                     // read-side involution
    for (int t = 0; t < nt; t++) {
        const int b = t & 1;
        short8 bfr[4];
#pragma unroll
        for (int ph = 0; ph < 4; ph++) {
            const int mh = ph & 1, kh = ph >> 1;
            short8 af[4];
#pragma unroll
            for (int i = 0; i < 4; i++)
                af[i] = *(const short8*)&As[b][kh][(wr * 128 + mh * 64 + i * 16 + l15) * 32 +
                                                   ((quad ^ rx) << 3)];
            if (mh == 0) {
#pragma unroll
                for (int j = 0; j < 4; j++)
                    bfr[j] = *(const short8*)&Bs[b][kh][(wc * 64 + j * 16 + l15) * 32 +
                                                        ((quad ^ rx) << 3)];
            }
            // stage calendar (targets sealed-dead regions only)
            if (ph == 0)      { if (t + 1 < nt) stage_region(t + 1, 1, 0); }
            else if (ph == 1) { if (t + 1 < nt) stage_region(t + 1, 1, 1); }
            else if (ph == 2) { if (t + 2 < nt) stage_region(t + 2, 0, 0); }
            else              { if (t + 2 < nt) stage_region(t + 2, 0, 1); }
            __builtin_amdgcn_s_barrier();
            asm volatile("s_waitcnt lgkmcnt(0)" ::: "memory");
            __builtin_amdgcn_s_setprio(1);
#pragma unroll
            for (int i = 0; i < 4; i++)
#pragma unroll
                for (int j = 0; j < 4; j++)
                    acc[mh * 4 + i][j] = __builtin_amdgcn_mfma_f32_16x16x32_bf16(
                        af[i], bfr[j], acc[mh * 4 + i][j], 0, 0, 0);
            __builtin_amdgcn_s_setprio(0);
            if (ph == 1) {
                if (t + 1 < nt) { asm volatile("s_waitcnt vmcnt(8)" ::: "memory"); }
                else            { asm volatile("s_waitcnt vmcnt(0)" ::: "memory"); }
            } else if (ph == 3) {
                if (t + 2 < nt)      { asm volatile("s_waitcnt vmcnt(8)" ::: "memory"); }
                else if (t + 1 < nt) { asm volatile("s_waitcnt vmcnt(4)" ::: "memory"); }
            }
            __builtin_amdgcn_s_barrier();
        }
    }

    // epilogue: C/D layout col=lane&15, row=quad*4+r (m89-verified)
    if (mode == 3) {
        float* po = (float*)out + (size_t)blockIdx.z * M * N;
#pragma unroll
        for (int j = 0; j < 4; j++) {
            const int col = n0 + wc * 64 + j * 16 + l15;
#pragma unroll
            for (int ig = 0; ig < 8; ig++) {
                const int row0 = m0 + wr * 128 + ig * 16 + quad * 4;
#pragma unroll
                for (int r = 0; r < 4; r++)
                    po[(size_t)(row0 + r) * N + col] = acc[ig][j][r];
            }
        }
        return;
    }
    if (mode == 2) {
        const int region = n0 >> 10;
        if (region < 2) {
            u16* o = (u16*)(region == 0 ? out : out_k);
#pragma unroll
            for (int j = 0; j < 4; j++) {
                const int col = n0 + wc * 64 + j * 16 + l15;
                const float bv = bias[col];
                const int cl = col & 1023;
#pragma unroll
                for (int ig = 0; ig < 8; ig++) {
                    const int row0 = m0 + wr * 128 + ig * 16 + quad * 4;
#pragma unroll
                    for (int r = 0; r < 4; r++)
                        o[(size_t)(row0 + r) * 1024 + cl] = f2bf(acc[ig][j][r] + bv);
                }
            }
        } else {
            u16* o = (u16*)out_v;
#pragma unroll
            for (int j = 0; j < 4; j++) {
                const int col = n0 + wc * 64 + j * 16 + l15;
                const float bv = bias[col];
                const int cl = col & 1023;
                const int h = cl >> 6, d = cl & 63;
#pragma unroll
                for (int ig = 0; ig < 8; ig++) {
                    const int row_base = m0 + wr * 128 + ig * 16 + quad * 4;
                    const int bb = row_base >> 11, tt = row_base & 2047;
                    u16 pk[4];
#pragma unroll
                    for (int r = 0; r < 4; r++) pk[r] = f2bf(acc[ig][j][r] + bv);
                    *(uint2*)&o[(((size_t)bb * 16 + h) * 64 + d) * 2048 + tt] = *(uint2*)pk;
                }
            }
        }
        return;
    }
    // mode 0: bias [+relu] [+res] -> bf16
#pragma unroll
    for (int j = 0; j < 4; j++) {
        const int col = n0 + wc * 64 + j * 16 + l15;
        const float bv = bias ? bias[col] : 0.f;
#pragma unroll
        for (int ig = 0; ig < 8; ig++) {
            const int row0 = m0 + wr * 128 + ig * 16 + quad * 4;
#pragma unroll
            for (int r = 0; r < 4; r++) {
                float v = acc[ig][j][r] + bv;
                if (relu) v = fmaxf(v, 0.f);
                const size_t idx = (size_t)(row0 + r) * N + col;
                if (res1) v += bf2f(res1[idx]);
                if (res2) v += bf2f(res2[idx]);
                ((u16*)out)[idx] = f2bf(v);
            }
        }
    }
}

// ---------------- split-K reduce: out = f(sum_z part[z]) --------------------
template <int TAG>
__global__ __launch_bounds__(256) void reduce_kernel(const float* __restrict__ part,
                                                     int nsplit, size_t MN,
                                                     const float* __restrict__ bias, int N,
                                                     const u16* __restrict__ res1,
                                                     const u16* __restrict__ res2,
                                                     void* __restrict__ out,
                                                     int relu, int final_store,
                                                     const int* __restrict__ flag) {
    const size_t i0 = ((size_t)blockIdx.x * 256 + threadIdx.x) * 4;
    float4 s = *(const float4*)&part[i0];
    for (int z = 1; z < nsplit; z++) {
        float4 p = *(const float4*)&part[(size_t)z * MN + i0];
        s.x += p.x; s.y += p.y; s.z += p.z; s.w += p.w;
    }
    const int col = (int)(i0 & (size_t)(N - 1));
    float v[4] = {s.x, s.y, s.z, s.w};
#pragma unroll
    for (int j = 0; j < 4; j++) {
        v[j] += bias[col + j];
        if (relu) v[j] = fmaxf(v[j], 0.f);
    }
    if (res1) {
        u16 r[4]; *(uint2*)r = *(const uint2*)&res1[i0];
#pragma unroll
        for (int j = 0; j < 4; j++) v[j] += bf2f(r[j]);
    }
    if (res2) {
        u16 r[4]; *(uint2*)r = *(const uint2*)&res2[i0];
#pragma unroll
        for (int j = 0; j < 4; j++) v[j] += bf2f(r[j]);
    }
    if (final_store && (*flag == 0)) {
        *(float4*)&((float*)out)[i0] = (float4){v[0], v[1], v[2], v[3]};
    } else {
        u16 o[4];
#pragma unroll
        for (int j = 0; j < 4; j++) o[j] = f2bf(v[j]);
        *(uint2*)&((u16*)out)[i0] = *(uint2*)o;
    }
}

// ---------------- flash attention v7: key-split chunks ----------------------
// Un-maxed online softmax (p = exp2(s*Cs)) means partials combine ADDITIVELY:
// O = sum O_c, l = sum l_c. Split each q-block's key range into chunks of <=8
// K-steps so all 2560 blocks are near-uniform (fixes the causal-imbalance
// occupancy collapse: 19% observed at 1024 variable-length blocks). qb 0..7
// (single chunk) normalize+store directly; qb>=8 write f32 partials, combined
// by flash_combine_kernel. Per-step compute path identical to verified v6.
template <int SPLIT>
__global__ __launch_bounds__(256) void flash_kernel(const u16* __restrict__ Q,
                                                    const u16* __restrict__ Kg,
                                                    const u16* __restrict__ VtG,
                                                    u16* __restrict__ O,
                                                    float* __restrict__ pO,
                                                    float* __restrict__ pL) {
    const int tid = threadIdx.x;
    const int wave = tid >> 6, lane = tid & 63;
    int qb, ch;
    if (SPLIT) {
        const int i = blockIdx.x;                  // long blocks first
        if (i < 32)      { qb = 31 - (i >> 2); ch = i & 3; }
        else if (i < 56) { const int j = i - 32; qb = 23 - j / 3; ch = j % 3; }
        else if (i < 72) { const int j = i - 56; qb = 15 - (j >> 1); ch = j & 1; }
        else             { qb = 7 - (i - 72); ch = 0; }
    } else {
        qb = 31 - blockIdx.x; ch = 0;
    }
    const int bh = blockIdx.y;
    const int t0 = qb * 64;
    const int steps = qb + 1;
    const int ktbeg = SPLIT ? ch * 8 : 0;
    const int ktend = SPLIT ? (steps < ktbeg + 8 ? steps : ktbeg + 8) : steps;
    const size_t base = ((size_t)(bh >> 4) * 2048) * 1024 + (size_t)(bh & 15) * 64;
    const size_t basev = (size_t)bh * 64 * 2048;

    __shared__ __align__(16) u16 Ks[2][64 * 64];
    __shared__ __align__(16) u16 Vt[2][64 * 64];
#if !__has_builtin(__builtin_amdgcn_mfma_f32_16x16x16bf16_1k)
    __shared__ __align__(16) u16 Ps[4][16 * 72];
#endif

    const int l15 = lane & 15, quad = lane >> 4;
    const int rmin = t0 + wave * 16;           // this wave's 16 q-rows

    // Q fragments (B-operand): lane holds Q[qrow=l15][d = st*32 + quad*8 ..+7]
    short8 qf[2];
    {
        const u16* qp = Q + base + (size_t)(rmin + l15) * 1024 + quad * 8;
        qf[0] = *(const short8*)qp;
        qf[1] = *(const short8*)(qp + 32);
    }

    const int slr = lane >> 3;                 // 0..7
    const int sc8 = (lane & 7) ^ slr;          // swizzled source col-chunk
    const int rb = wave * 16;                  // 4 waves x 16 rows = 64-row tile

    auto stage = [&](int kt, int bufi) {
        gl_lds16(Kg + base + (size_t)(kt * 64 + rb + slr) * 1024 + sc8 * 8,
                 &Ks[bufi][rb * 64 + lane * 8]);
        gl_lds16(Kg + base + (size_t)(kt * 64 + rb + 8 + slr) * 1024 + sc8 * 8,
                 &Ks[bufi][(rb + 8) * 64 + lane * 8]);
        gl_lds16(VtG + basev + (size_t)(rb + slr) * 2048 + kt * 64 + sc8 * 8,
                 &Vt[bufi][rb * 64 + lane * 8]);
        gl_lds16(VtG + basev + (size_t)(rb + 8 + slr) * 2048 + kt * 64 + sc8 * 8,
                 &Vt[bufi][(rb + 8) * 64 + lane * 8]);
    };

    float l_part = 0.f;
    f32x4 oacc[4];
#pragma unroll
    for (int jt = 0; jt < 4; jt++) oacc[jt] = (f32x4){0.f, 0.f, 0.f, 0.f};

    const float Cs = 0.125f * 1.44269504f;     // scale * log2(e)

    stage(ktbeg, 0);
    __syncthreads();

    for (int kt = ktbeg; kt < ktend; kt++) {
        const int cur = kt & 1;
        if (kt + 1 < ktend) stage(kt + 1, cur ^ 1);   // prefetch overlaps compute

        // K fragments (A-operand): lane holds K[key=j*16+l15][d chunk st*4+quad]
        short8 kf[2][4];
#pragma unroll
        for (int st = 0; st < 2; st++)
#pragma unroll
            for (int j = 0; j < 4; j++)
                kf[st][j] = *(const short8*)&Ks[cur][(j * 16 + l15) * 64 +
                                                     (((st * 4 + quad) ^ (l15 & 7)) * 8)];
#if __has_builtin(__builtin_amdgcn_mfma_f32_16x16x16bf16_1k)
        // V b64 fragments for 16x16x16 PV: lane holds V[key=j*16+quad*4+jj][d=jt*16+l15]
        short4v vf[4][4];
#pragma unroll
        for (int j = 0; j < 4; j++) {
            int k8 = j * 2 + (quad >> 1);      // data key-chunk
#pragma unroll
            for (int jt = 0; jt < 4; jt++) {
                int d = jt * 16 + l15;
                vf[j][jt] = *(const short4v*)&Vt[cur][d * 64 + ((k8 ^ (d & 7)) * 8) +
                                                      (quad & 1) * 4];
            }
        }
#else
        short8 vf[2][4];
#pragma unroll
        for (int st = 0; st < 2; st++)
#pragma unroll
            for (int jt = 0; jt < 4; jt++) {
                int d = jt * 16 + l15;
                vf[st][jt] = *(const short8*)&Vt[cur][d * 64 + (((st * 4 + quad) ^ (d & 7)) * 8)];
            }
#endif

        // S^T = K Q^T : lane gets qrow=l15, keys j*16+quad*4+r
        f32x4 s[4];
#pragma unroll
        for (int j = 0; j < 4; j++) s[j] = (f32x4){0.f, 0.f, 0.f, 0.f};
#pragma unroll
        for (int st = 0; st < 2; st++)
#pragma unroll
            for (int j = 0; j < 4; j++)
                s[j] = __builtin_amdgcn_mfma_f32_16x16x32_bf16(kf[st][j], qf[st], s[j], 0, 0, 0);

        const int qrow = rmin + l15;
        const bool needmask = (kt * 64 + 63 > rmin);
        float lp = l_part;
        short4v pj[4];
#pragma unroll
        for (int j = 0; j < 4; j++) {
            union { short4v v; u16 u[4]; } pk;
#pragma unroll
            for (int r = 0; r < 4; r++) {
                float p = __builtin_amdgcn_exp2f(s[j][r] * Cs);
                int key = kt * 64 + j * 16 + quad * 4 + r;
                if (needmask && key > qrow) p = 0.f;
                lp += p;
                pk.u[r] = f2bf_fast(p);
            }
            pj[j] = pk.v;
        }
        l_part = lp;

#if __has_builtin(__builtin_amdgcn_mfma_f32_16x16x16bf16_1k)
        // O += P V, P straight from registers (A-frag match)
#pragma unroll
        for (int jt = 0; jt < 4; jt++)
#pragma unroll
            for (int j = 0; j < 4; j++)
                oacc[jt] = __builtin_amdgcn_mfma_f32_16x16x16bf16_1k(pj[j], vf[j][jt],
                                                                     oacc[jt], 0, 0, 0);
#else
        // fallback: b64 P-writes to padded LDS, b128 reads as 16x16x32 A-frag
        u16* Pw = Ps[wave];
#pragma unroll
        for (int j = 0; j < 4; j++)
            *(short4v*)&Pw[l15 * 72 + j * 16 + quad * 4] = pj[j];
#pragma unroll
        for (int st = 0; st < 2; st++) {
            short8 pf = *(const short8*)&Pw[l15 * 72 + st * 32 + quad * 8];
#pragma unroll
            for (int jt = 0; jt < 4; jt++)
                oacc[jt] = __builtin_amdgcn_mfma_f32_16x16x32_bf16(pf, vf[st][jt],
                                                                  oacc[jt], 0, 0, 0);
        }
#endif
        __syncthreads();
    }

    // l reduction: l lives per qrow=l15; reduce across quads
    float lf = l_part;
    lf += __shfl_xor(lf, 16, 64);
    lf += __shfl_xor(lf, 32, 64);

    if (SPLIT && steps > 8) {
        // multi-chunk q-block: write un-normalized f32 partials
        const size_t ib = ((size_t)bh * 24 + (qb - 8)) * 4 + ch;
        float* po = pO + ib * 4096;
#pragma unroll
        for (int jt = 0; jt < 4; jt++)
#pragma unroll
            for (int r = 0; r < 4; r++)
                po[(wave * 16 + quad * 4 + r) * 64 + jt * 16 + l15] = oacc[jt][r];
        if (quad == 0) pL[ib * 64 + wave * 16 + l15] = lf;
        return;
    }

    // single-chunk: normalize and store bf16
    {
        float inv[4];
#pragma unroll
        for (int r = 0; r < 4; r++) inv[r] = 1.f / __shfl(lf, quad * 4 + r, 64);
#pragma unroll
        for (int jt = 0; jt < 4; jt++) {
            int d = jt * 16 + l15;
#pragma unroll
            for (int r = 0; r < 4; r++) {
                int t = rmin + quad * 4 + r;
                O[base + (size_t)t * 1024 + d] = f2bf(oacc[jt][r] * inv[r]);
            }
        }
    }
}

// ---------------- flash combine: O = (sum_c O_c) / (sum_c l_c) --------------
__global__ __launch_bounds__(256) void flash_combine_kernel(const float* __restrict__ pO,
                                                            const float* __restrict__ pL,
                                                            u16* __restrict__ O) {
    const int qj = blockIdx.x;                 // 0..23 -> qb = qj + 8
    const int bh = blockIdx.y;
    const int qb = qj + 8;
    const int nch = (qb >> 3) + 1;             // 2, 3 or 4 chunks
    const int tid = threadIdx.x;
    const int row = tid >> 2;                  // 0..63
    const int d0 = (tid & 3) * 16;
    const size_t ib = ((size_t)bh * 24 + qj) * 4;

    float acc[16];
#pragma unroll
    for (int k = 0; k < 16; k++) acc[k] = 0.f;
    float lsum = 0.f;
    for (int c = 0; c < nch; c++) {
        const float* po = pO + (ib + c) * 4096 + row * 64 + d0;
#pragma unroll
        for (int v = 0; v < 4; v++) {
            float4 f = *(const float4*)&po[v * 4];
            acc[v * 4 + 0] += f.x; acc[v * 4 + 1] += f.y;
            acc[v * 4 + 2] += f.z; acc[v * 4 + 3] += f.w;
        }
        lsum += pL[(ib + c) * 64 + row];
    }
    const float inv = 1.f / lsum;
    u16 o[16];
#pragma unroll
    for (int k = 0; k < 16; k++) o[k] = f2bf(acc[k] * inv);
    const size_t base = ((size_t)(bh >> 4) * 2048) * 1024 + (size_t)(bh & 15) * 64;
    const int t = qb * 64 + row;
    u16* op = &O[base + (size_t)t * 1024 + d0];
    *(uint4*)op = ((uint4*)o)[0];
    *(uint4*)(op + 8) = ((uint4*)o)[1];
}

extern "C" void kernel_launch(void* const* d_in, const int* in_sizes, int n_in,
                              void* d_out, int out_size, void* d_ws, size_t ws_size,
                              hipStream_t stream) {
    (void)in_sizes; (void)n_in; (void)out_size;
    const void* x   = d_in[0];
    // d_in[1] = attn_mask (int32, pure causal) -- implemented directly
    const void* Wq  = d_in[2];  const void* bq  = d_in[3];
    const void* Wk  = d_in[4];  const void* bk  = d_in[5];
    const void* Wv  = d_in[6];  const void* bv  = d_in[7];
    const void* Wo  = d_in[8];  const void* bo  = d_in[9];
    const void* g1  = d_in[10]; const void* be1 = d_in[11];
    const void* g2  = d_in[12]; const void* be2 = d_in[13];
    const void* W1  = d_in[14]; const void* bf1 = d_in[15];
    const void* W2  = d_in[16]; const void* bf2 = d_in[17];
    const void* Wd  = d_in[18]; const void* bd  = d_in[19];
    const void* Wu  = d_in[20]; const void* bu  = d_in[21];

    uint8_t* w8 = (uint8_t*)d_ws;
    int* flag = (int*)w8;                    // 64 B header
    float* pf = (float*)(w8 + 64);           // f32 param pool
    u16* wsb = (u16*)(w8 + 64 + 65536);      // bf16 arena

    const size_t M1 = 1024ull * 1024ull;
    u16* WqT = wsb;                          // Wq/Wk/Wv transposed, contiguous 3072xK
    u16* WkT = wsb + 1 * M1;
    u16* WvT = wsb + 2 * M1;
    u16* WoT = wsb + 3 * M1;
    u16* W1T = wsb + 4 * M1;                 // 4M
    u16* W2T = wsb + 8 * M1;                 // 4M
    u16* WdT = wsb + 12 * M1;                // 64K
    u16* WuT = wsb + 12 * M1 + 65536;        // 64K
    u16* S0  = wsb + 12 * M1 + 131072;
    u16* Areg = S0;                          // xb
    u16* Breg = S0 + 4 * M1;                 // xn -> attn
    u16* ff1  = S0;                          // 16M spans Areg+Breg+8M fresh
    u16* Creg = S0 + 16 * M1;                // q -> xn2 -> bot
    u16* Dreg = S0 + 20 * M1;                // k -> x1
    u16* Ereg = S0 + 24 * M1;                // VtG -> hh
    u16* xb = Areg;
    u16* xn = Breg; u16* attn = Breg;
    u16* q = Creg;  u16* xn2 = Creg;  u16* bot = Creg;
    u16* kk_ = Dreg; u16* x1 = Dreg;
    u16* VtG = Ereg; u16* hh = Ereg;

    // split-K partial buffer: 64 MB f32 after the bf16 arena
    // (time-shared: flash partials [48MB O + 1MB l] -> Wo split-K -> FFN2 split-K)
    const size_t arena_bytes = (size_t)(64 + 65536) + (40 * M1 + 131072) * 2;
    float* partf = (float*)(w8 + ((arena_bytes + 255) & ~(size_t)255));
    const size_t need = ((arena_bytes + 255) & ~(size_t)255) + 4ull * 4 * M1 * 4;  // Z=4 x 4M f32
    const bool sk = ws_size >= need;
    float* flL = partf + 14 * M1;            // flash l partials at +56MB

    float* bqkv_f = pf + 0;    // bq,bk,bv contiguous (3072)
    float* bo_f  = pf + 3072;
    float* bf1_f = pf + 4096;  float* bf2_f = pf + 8192;
    float* bd_f  = pf + 9216;  float* bu_f  = pf + 9280;
    float* g1_f  = pf + 10304; float* be1_f = pf + 11328;
    float* g2_f  = pf + 12352; float* be2_f = pf + 13376;

    detect_kernel<<<1, 256, 0, stream>>>((const unsigned*)x, flag);

    ParamCvt pc;
    const void* srcs[12] = {bq, bk, bv, bo, bf1, bf2, bd, bu, g1, be1, g2, be2};
    int offs[12] = {0, 1024, 2048, 3072, 4096, 8192, 9216, 9280, 10304, 11328, 12352, 13376};
    int ns[12]   = {1024, 1024, 1024, 1024, 4096, 1024, 64, 1024, 1024, 1024, 1024, 1024};
    for (int i = 0; i < 12; i++) { pc.src[i] = srcs[i]; pc.off[i] = offs[i]; pc.n[i] = ns[i]; }
    param_cvt_kernel<<<12, 256, 0, stream>>>(pc, pf, flag);

    cvt_x_kernel<<<4096, 256, 0, stream>>>(x, xb, flag);

    TAll ta;
    const void* tsrc[8] = {Wq, Wk, Wv, Wo, W1, W2, Wd, Wu};
    u16* tdst[8] = {WqT, WkT, WvT, WoT, W1T, W2T, WdT, WuT};
    int tR[8] = {1024, 1024, 1024, 1024, 1024, 4096, 1024, 64};
    int tC[8] = {1024, 1024, 1024, 1024, 4096, 1024, 64, 1024};
    int acc_off = 0;
    for (int i = 0; i < 8; i++) {
        ta.src[i] = tsrc[i]; ta.dst[i] = tdst[i];
        ta.R[i] = tR[i]; ta.C[i] = tC[i];
        ta.off[i] = acc_off;
        acc_off += (tR[i] >> 5) * (tC[i] >> 5);
    }
    transpose_all_kernel<<<acc_off, 256, 0, stream>>>(ta, flag);

    ln_kernel<<<4096, 256, 0, stream>>>(xb, g1_f, be1_f, xn);
    // TAG 0: fused QKV (N=3072, V written transposed per-head into VtG), 256^2 pipeline
    gemm256_kernel<0><<<dim3(12, 16), 512, 0, stream>>>(xn, WqT, bqkv_f, nullptr, nullptr,
                                                        q, kk_, VtG, 4096, 3072, 1024, 0, 2, flag);
    if (sk) {
        flash_kernel<1><<<dim3(80, 32), 256, 0, stream>>>(q, kk_, VtG, attn, partf, flL);
        flash_combine_kernel<<<dim3(24, 32), 256, 0, stream>>>(partf, flL, attn);
    } else {
        flash_kernel<0><<<dim3(32, 32), 256, 0, stream>>>(q, kk_, VtG, attn, nullptr, nullptr);
    }
    // TAG 1: Wo projection + residual (split-K 4, 256^2 pipeline, nt=4)
    if (sk) {
        gemm256_kernel<1><<<dim3(4, 16, 4), 512, 0, stream>>>(attn, WoT, nullptr, nullptr, nullptr,
                                                              partf, nullptr, nullptr, 4096, 1024, 1024, 0, 3, flag);
        reduce_kernel<1><<<4096, 256, 0, stream>>>(partf, 4, 4 * M1, bo_f, 1024, xb, nullptr,
                                                   x1, 0, 0, flag);
    } else {
        gemm_bt_kernel<1><<<dim3(8, 32), 256, 0, stream>>>(attn, WoT, bo_f, xb, nullptr,
                                                           x1, nullptr, nullptr, 4096, 1024, 1024, 0, 0, flag);
    }
    ln_kernel<<<4096, 256, 0, stream>>>(x1, g2_f, be2_f, xn2);
    // TAG 2: FFN1 (relu), 256^2 pipeline
    gemm256_kernel<2><<<dim3(16, 16), 512, 0, stream>>>(xn2, W1T, bf1_f, nullptr, nullptr,
                                                        ff1, nullptr, nullptr, 4096, 4096, 1024, 1, 0, flag);
    // TAG 3: FFN2 (split-K 4, 256^2 pipeline, nt=16)
    if (sk) {
        gemm256_kernel<3><<<dim3(4, 16, 4), 512, 0, stream>>>(ff1, W2T, nullptr, nullptr, nullptr,
                                                              partf, nullptr, nullptr, 4096, 1024, 4096, 0, 3, flag);
        reduce_kernel<3><<<4096, 256, 0, stream>>>(partf, 4, 4 * M1, bf2_f, 1024, nullptr, nullptr,
                                                   hh, 0, 0, flag);
    } else {
        gemm_bt_kernel<3><<<dim3(8, 32), 256, 0, stream>>>(ff1, W2T, bf2_f, nullptr, nullptr,
                                                           hh, nullptr, nullptr, 4096, 1024, 4096, 0, 0, flag);
    }
    // TAG 4: adapter down (relu, split-K 8) -- N=64, stays on 128^2 kernel
    if (sk) {
        gemm_bt_kernel<4><<<dim3(1, 32, 8), 256, 0, stream>>>(hh, WdT, nullptr, nullptr, nullptr,
                                                              partf, nullptr, nullptr, 4096, 64, 1024, 1, 3, flag);
        reduce_kernel<4><<<256, 256, 0, stream>>>(partf, 8, 256 * 1024, bd_f, 64, nullptr, nullptr,
                                                  bot, 1, 0, flag);
    } else {
        gemm_bt_kernel<4><<<dim3(1, 32), 256, 0, stream>>>(hh, WdT, bd_f, nullptr, nullptr,
                                                           bot, nullptr, nullptr, 4096, 64, 1024, 1, 0, flag);
    }
    // TAG 5: adapter up + residuals (final store) -- K=64, stays on 128^2 kernel
    gemm_bt_kernel<5><<<dim3(8, 32), 256, 0, stream>>>(bot, WuT, bu_f, hh, x1,
                                                       d_out, nullptr, nullptr, 4096, 1024, 64, 0, 1, flag);
}

// Round 6
// 461.212 us; speedup vs baseline: 1.0621x; 1.0437x over previous
//
#include <hip/hip_runtime.h>
#include <cstdint>
#include <cstddef>

typedef unsigned short u16;
typedef __attribute__((ext_vector_type(4))) short short4v;
typedef __attribute__((ext_vector_type(8))) short short8;
typedef __attribute__((ext_vector_type(4))) float f32x4;

__device__ __forceinline__ float bf2f(u16 h) { return __uint_as_float(((unsigned)h) << 16); }
__device__ __forceinline__ u16 f2bf(float f) {
    unsigned u = __float_as_uint(f);
    unsigned r = (u + 0x7fffu + ((u >> 16) & 1u)) >> 16;
    return (u16)r;
}
// round-half-up: <=0.5 ULP, 2 VALU ops (flash inner loop)
__device__ __forceinline__ u16 f2bf_fast(float f) {
    return (u16)((__float_as_uint(f) + 0x8000u) >> 16);
}

__device__ __forceinline__ void gl_lds16(const void* g, void* l) {
    __builtin_amdgcn_global_load_lds((const __attribute__((address_space(1))) void*)g,
                                     (__attribute__((address_space(3))) void*)l, 16, 0, 0);
}

// ---------------- dtype detection: flag=1 if inputs are bf16, 0 if f32 ------
__global__ __launch_bounds__(256) void detect_kernel(const unsigned* __restrict__ x,
                                                     int* __restrict__ flag) {
    __shared__ int cnt[256];
    int c = 0;
    for (int i = threadIdx.x; i < 4096; i += 256) {
        unsigned lo = x[i] & 0xFFFFu;
        unsigned e = (lo >> 7) & 0xFFu;
        c += (e >= 100u && e <= 150u) ? 1 : 0;
    }
    cnt[threadIdx.x] = c;
    __syncthreads();
    for (int s = 128; s > 0; s >>= 1) {
        if (threadIdx.x < s) cnt[threadIdx.x] += cnt[threadIdx.x + s];
        __syncthreads();
    }
    if (threadIdx.x == 0) *flag = (cnt[0] > 2048) ? 1 : 0;
}

// ---------------- param convert (biases/gamma/beta) -> f32 pool -------------
struct ParamCvt {
    const void* src[12];
    int off[12];
    int n[12];
};
__global__ __launch_bounds__(256) void param_cvt_kernel(ParamCvt pc, float* __restrict__ dst,
                                                        const int* __restrict__ flag) {
    const int bf = *flag;
    const int s = blockIdx.x;
    const void* sp = pc.src[s];
    float* dp = dst + pc.off[s];
    const int n = pc.n[s];
    for (int i = threadIdx.x; i < n; i += 256)
        dp[i] = bf ? bf2f(((const u16*)sp)[i]) : ((const float*)sp)[i];
}

// ---------------- x -> bf16 (4 elems/thread) --------------------------------
__global__ __launch_bounds__(256) void cvt_x_kernel(const void* __restrict__ x,
                                                    u16* __restrict__ xb,
                                                    const int* __restrict__ flag) {
    const int bf = *flag;
    const int i0 = (blockIdx.x * 256 + threadIdx.x) * 4;
    u16 o[4];
    if (bf) {
        *(uint2*)o = *(const uint2*)((const u16*)x + i0);
    } else {
        float4 f = *(const float4*)((const float*)x + i0);
        o[0] = f2bf(f.x); o[1] = f2bf(f.y); o[2] = f2bf(f.z); o[3] = f2bf(f.w);
    }
    *(uint2*)&xb[i0] = *(uint2*)o;
}

// ---------------- fused transpose+cast of all 8 weights ---------------------
struct TAll {
    const void* src[8];
    u16* dst[8];
    int R[8], C[8];
    int off[8];
};
__global__ __launch_bounds__(256) void transpose_all_kernel(TAll t,
                                                            const int* __restrict__ flag) {
    const int bf = *flag;
    __shared__ u16 tile[32][33];
    int bid = blockIdx.x;
    int m = 0;
#pragma unroll
    for (int i = 1; i < 8; i++) m = (bid >= t.off[i]) ? i : m;
    int local = bid - t.off[m];
    const int R = t.R[m], C = t.C[m];
    const int tilesx = C >> 5;
    const int bx = local % tilesx, by = local / tilesx;
    const void* src = t.src[m];
    u16* dst = t.dst[m];
    const int tx = threadIdx.x & 31, ty = threadIdx.x >> 5;   // ty 0..7
#pragma unroll
    for (int i = 0; i < 32; i += 8) {
        size_t idx = (size_t)(by * 32 + ty + i) * C + bx * 32 + tx;
        tile[ty + i][tx] = bf ? ((const u16*)src)[idx] : f2bf(((const float*)src)[idx]);
    }
    __syncthreads();
#pragma unroll
    for (int i = 0; i < 32; i += 8)
        dst[(size_t)(bx * 32 + ty + i) * R + by * 32 + tx] = tile[tx][ty + i];
}

// ---------------- LayerNorm over C=1024 (bf16 in, f32 params, bf16 out) -----
__global__ __launch_bounds__(256) void ln_kernel(const u16* __restrict__ X,
                                                 const float* __restrict__ G,
                                                 const float* __restrict__ Be,
                                                 u16* __restrict__ Y) {
    const int row = blockIdx.x;
    const int tid = threadIdx.x;
    const int lane = tid & 63, wave = tid >> 6;
    const u16* xr = X + (size_t)row * 1024;
    u16 vbuf[4];
    *(uint2*)vbuf = *(const uint2*)&xr[tid * 4];
    float f[4];
    float s = 0.f, sq = 0.f;
#pragma unroll
    for (int j = 0; j < 4; j++) { f[j] = bf2f(vbuf[j]); s += f[j]; sq += f[j] * f[j]; }
#pragma unroll
    for (int m = 1; m < 64; m <<= 1) { s += __shfl_xor(s, m, 64); sq += __shfl_xor(sq, m, 64); }
    __shared__ float rs_[4], rq_[4];
    if (lane == 0) { rs_[wave] = s; rq_[wave] = sq; }
    __syncthreads();
    float S = rs_[0] + rs_[1] + rs_[2] + rs_[3];
    float Q2 = rq_[0] + rq_[1] + rq_[2] + rq_[3];
    float mean = S * (1.f / 1024.f);
    float var = Q2 * (1.f / 1024.f) - mean * mean;
    float rstd = rsqrtf(var + 1e-5f);
    u16 o[4];
#pragma unroll
    for (int j = 0; j < 4; j++) {
        int c2 = tid * 4 + j;
        float y = (f[j] - mean) * rstd * G[c2] + Be[c2];
        o[j] = f2bf(y);
    }
    *(uint2*)&Y[(size_t)row * 1024 + tid * 4] = *(uint2*)o;
}

// ---------------- GEMM 128x128 (legacy path, small shapes) ------------------
// out(MxN) = A(MxK) @ Bt(NxK)^T + bias (+res1+res2); split-K via gridDim.z.
template <int TAG>
__global__ __launch_bounds__(256) void gemm_bt_kernel(const u16* __restrict__ A,
                                                      const u16* __restrict__ Bt,
                                                      const float* __restrict__ bias,
                                                      const u16* __restrict__ res1,
                                                      const u16* __restrict__ res2,
                                                      void* __restrict__ out,
                                                      void* __restrict__ out_k,
                                                      void* __restrict__ out_v,
                                                      int M, int N, int K, int relu, int mode,
                                                      const int* __restrict__ flag) {
    __shared__ __align__(16) u16 As[2][128 * 32];
    __shared__ __align__(16) u16 Bs[2][128 * 32];
    const int tid = threadIdx.x;
    const int wave = tid >> 6, lane = tid & 63;
    const int m0 = blockIdx.y * 128, n0 = blockIdx.x * 128;
    const int wm = (wave >> 1) * 64, wn = (wave & 1) * 64;

    f32x4 acc[4][4];
#pragma unroll
    for (int i = 0; i < 4; i++)
#pragma unroll
        for (int j = 0; j < 4; j++) acc[i][j] = (f32x4){0.f, 0.f, 0.f, 0.f};

    const int lr4 = lane >> 2;                         // 0..15 (row in 16-row chunk)
    const int sc4 = ((lane & 3) ^ ((lane >> 3) & 3));  // swizzled source col-chunk

    const int Ksub = K / (int)gridDim.z;
    const int kbeg = blockIdx.z * Ksub;

    auto stage = [&](int k0, int bufi) {
#pragma unroll
        for (int c = 0; c < 2; c++) {
            int rbase = wave * 32 + c * 16;
            int arow = m0 + rbase + lr4;
            int brow = n0 + rbase + lr4;
            if (brow > N - 1) brow = N - 1;
            gl_lds16(A + (size_t)arow * K + k0 + sc4 * 8, &As[bufi][rbase * 32 + lane * 8]);
            gl_lds16(Bt + (size_t)brow * K + k0 + sc4 * 8, &Bs[bufi][rbase * 32 + lane * 8]);
        }
    };

    stage(kbeg, 0);
    __syncthreads();
    const int nk = Ksub >> 5;
    for (int ik = 0; ik < nk; ik++) {
        const int cur = ik & 1;
        if (ik + 1 < nk) stage(kbeg + ((ik + 1) << 5), cur ^ 1);
        short8 af[4], bf[4];
        const int cc = (lane >> 4) ^ ((lane >> 1) & 3);  // swizzled read chunk
#pragma unroll
        for (int i = 0; i < 4; i++)
            af[i] = *(const short8*)&As[cur][(wm + i * 16 + (lane & 15)) * 32 + cc * 8];
#pragma unroll
        for (int j = 0; j < 4; j++)
            bf[j] = *(const short8*)&Bs[cur][(wn + j * 16 + (lane & 15)) * 32 + cc * 8];
#pragma unroll
        for (int i = 0; i < 4; i++)
#pragma unroll
            for (int j = 0; j < 4; j++)
                acc[i][j] = __builtin_amdgcn_mfma_f32_16x16x32_bf16(af[i], bf[j], acc[i][j], 0, 0, 0);
        __syncthreads();
    }

    // epilogue: C/D layout col=lane&15, row=(lane>>4)*4+r  (m89-verified)
    if (mode == 3) {
        float* po = (float*)out + (size_t)blockIdx.z * M * N;
#pragma unroll
        for (int j = 0; j < 4; j++) {
            int col = n0 + wn + j * 16 + (lane & 15);
            if (col >= N) continue;
#pragma unroll
            for (int i = 0; i < 4; i++)
#pragma unroll
                for (int r = 0; r < 4; r++) {
                    int row = m0 + wm + i * 16 + (lane >> 4) * 4 + r;
                    po[(size_t)row * N + col] = acc[i][j][r];
                }
        }
        return;
    }

    const int f32out = (mode == 1) && (*flag == 0);
#pragma unroll
    for (int j = 0; j < 4; j++) {
        int col = n0 + wn + j * 16 + (lane & 15);
        if (col >= N) continue;
        float bv = bias ? bias[col] : 0.f;
#pragma unroll
        for (int i = 0; i < 4; i++) {
#pragma unroll
            for (int r = 0; r < 4; r++) {
                int row = m0 + wm + i * 16 + (lane >> 4) * 4 + r;
                float v = acc[i][j][r] + bv;
                if (relu) v = fmaxf(v, 0.f);
                size_t idx = (size_t)row * N + col;
                if (res1) v += bf2f(res1[idx]);
                if (res2) v += bf2f(res2[idx]);
                if (f32out) ((float*)out)[idx] = v;
                else ((u16*)out)[idx] = f2bf(v);
            }
        }
    }
}

// ---------------- GEMM 128x128 / 8 waves, K-region deep pipeline ------------
// Scale-down of the verified 256^2 K-region calendar (round-2). BK=64, 8
// waves (4 row-groups x 2 col-groups, 32x64 per wave), LDS 64KB -> 2 blocks/CU
// where the grid supplies them (QKV 768, FFN1 1024 blocks): cross-block
// overlap hides barrier/prologue/epilogue bubbles. Regions are K-MAJOR:
// As[buf][kh] = 128 rows x 32-wide k-half, 8KB. Phases per tile: ph0=k0,
// ph1=k1 (6 ds_read_b128 + 8 MFMA each). Calendar (race-free, same algebra
// as the 256^2 kernel): t.ph0 stages (t+1,k1); t.ph1 stages (t+2,k0).
// Counted waits (2 loads/stage): ph0-end vmcnt(4) covers (t,k1); ph1-end
// vmcnt(4) covers (t+1,k0); tails 2/0. Never vmcnt(0) in steady state.
// Swizzle involution phys_chunk = logical ^ ((row>>1)&3) on BOTH the global
// source and the ds_read (rule #21). Requires M%128==0, N%128==0, nt>=2.
template <int TAG>
__global__ __launch_bounds__(512, 4) void gemm128_kernel(const u16* __restrict__ A,
                                                         const u16* __restrict__ Bt,
                                                         const float* __restrict__ bias,
                                                         const u16* __restrict__ res1,
                                                         const u16* __restrict__ res2,
                                                         void* __restrict__ out,
                                                         void* __restrict__ out_k,
                                                         void* __restrict__ out_v,
                                                         int M, int N, int K, int relu, int mode,
                                                         const int* __restrict__ flag) {
    (void)flag; (void)M;
    __shared__ __align__(16) u16 As[2][2][128 * 32];   // [buf][kh][row*32+chunk*8] = 8KB each
    __shared__ __align__(16) u16 Bs[2][2][128 * 32];
    const int tid = threadIdx.x;
    const int wave = tid >> 6, lane = tid & 63;
    const int l15 = lane & 15, quad = lane >> 4;
    const int wr = wave & 3, wc = wave >> 2;           // 4x2 wave grid: 32x64 per wave
    const int m0 = blockIdx.y * 128, n0 = blockIdx.x * 128;
    const int nt = K >> 6;

    // staging: wave covers rows [wave*16,+16); lane l -> phys row l>>2,
    // phys chunk l&3; source logical chunk pre-swizzled (same involution)
    const int rsub = lane >> 2;                        // 0..15
    const int logc = (lane & 3) ^ ((rsub >> 1) & 3);

    auto stage_pair = [&](int t, int kh) {
        const int buf = t & 1;
        const int kk = (t << 6) + (kh << 5) + logc * 8;
        const int roff = wave * 16 + rsub;
        gl_lds16(A + (size_t)(m0 + roff) * K + kk, &As[buf][kh][wave * 512 + lane * 8]);
        gl_lds16(Bt + (size_t)(n0 + roff) * K + kk, &Bs[buf][kh][wave * 512 + lane * 8]);
    };

    f32x4 acc[2][4];
#pragma unroll
    for (int i = 0; i < 2; i++)
#pragma unroll
        for (int j = 0; j < 4; j++) acc[i][j] = (f32x4){0.f, 0.f, 0.f, 0.f};

    // prologue: (0,k0), (0,k1), (1,k0); wait tile0.k0 complete (4 newer loads)
    stage_pair(0, 0);
    stage_pair(0, 1);
    stage_pair(1, 0);
    asm volatile("s_waitcnt vmcnt(4)" ::: "memory");
    __builtin_amdgcn_s_barrier();

    const int rx = (l15 >> 1) & 3;                     // read-side involution
    for (int t = 0; t < nt; t++) {
        const int b = t & 1;
#pragma unroll
        for (int ph = 0; ph < 2; ph++) {
            const int kh = ph;
            short8 af[2], bfr[4];
#pragma unroll
            for (int i = 0; i < 2; i++)
                af[i] = *(const short8*)&As[b][kh][(wr * 32 + i * 16 + l15) * 32 +
                                                   ((quad ^ rx) << 3)];
#pragma unroll
            for (int j = 0; j < 4; j++)
                bfr[j] = *(const short8*)&Bs[b][kh][(wc * 64 + j * 16 + l15) * 32 +
                                                    ((quad ^ rx) << 3)];
            // stage calendar (targets sealed-dead regions only)
            if (ph == 0) { if (t + 1 < nt) stage_pair(t + 1, 1); }
            else         { if (t + 2 < nt) stage_pair(t + 2, 0); }
            __builtin_amdgcn_s_barrier();
            asm volatile("s_waitcnt lgkmcnt(0)" ::: "memory");
            __builtin_amdgcn_s_setprio(1);
#pragma unroll
            for (int i = 0; i < 2; i++)
#pragma unroll
                for (int j = 0; j < 4; j++)
                    acc[i][j] = __builtin_amdgcn_mfma_f32_16x16x32_bf16(
                        af[i], bfr[j], acc[i][j], 0, 0, 0);
            __builtin_amdgcn_s_setprio(0);
            if (ph == 0) {
                if (t + 1 < nt) { asm volatile("s_waitcnt vmcnt(4)" ::: "memory"); }
                else            { asm volatile("s_waitcnt vmcnt(0)" ::: "memory"); }
            } else {
                if (t + 2 < nt)      { asm volatile("s_waitcnt vmcnt(4)" ::: "memory"); }
                else if (t + 1 < nt) { asm volatile("s_waitcnt vmcnt(2)" ::: "memory"); }
            }
            __builtin_amdgcn_s_barrier();
        }
    }

    // epilogue: C/D layout col=lane&15, row=quad*4+r (m89-verified)
    if (mode == 2) {
        const int region = n0 >> 10;
        if (region < 2) {
            u16* o = (u16*)(region == 0 ? out : out_k);
#pragma unroll
            for (int j = 0; j < 4; j++) {
                const int col = n0 + wc * 64 + j * 16 + l15;
                const float bv = bias[col];
                const int cl = col & 1023;
#pragma unroll
                for (int i = 0; i < 2; i++) {
                    const int row0 = m0 + wr * 32 + i * 16 + quad * 4;
#pragma unroll
                    for (int r = 0; r < 4; r++)
                        o[(size_t)(row0 + r) * 1024 + cl] = f2bf(acc[i][j][r] + bv);
                }
            }
        } else {
            u16* o = (u16*)out_v;
#pragma unroll
            for (int j = 0; j < 4; j++) {
                const int col = n0 + wc * 64 + j * 16 + l15;
                const float bv = bias[col];
                const int cl = col & 1023;
                const int h = cl >> 6, d = cl & 63;
#pragma unroll
                for (int i = 0; i < 2; i++) {
                    const int row_base = m0 + wr * 32 + i * 16 + quad * 4;
                    const int bb = row_base >> 11, tt = row_base & 2047;
                    u16 pk[4];
#pragma unroll
                    for (int r = 0; r < 4; r++) pk[r] = f2bf(acc[i][j][r] + bv);
                    *(uint2*)&o[(((size_t)bb * 16 + h) * 64 + d) * 2048 + tt] = *(uint2*)pk;
                }
            }
        }
        return;
    }
    // mode 0: bias [+relu] [+res] -> bf16
#pragma unroll
    for (int j = 0; j < 4; j++) {
        const int col = n0 + wc * 64 + j * 16 + l15;
        const float bv = bias ? bias[col] : 0.f;
#pragma unroll
        for (int i = 0; i < 2; i++) {
            const int row0 = m0 + wr * 32 + i * 16 + quad * 4;
#pragma unroll
            for (int r = 0; r < 4; r++) {
                float v = acc[i][j][r] + bv;
                if (relu) v = fmaxf(v, 0.f);
                const size_t idx = (size_t)(row0 + r) * N + col;
                if (res1) v += bf2f(res1[idx]);
                if (res2) v += bf2f(res2[idx]);
                ((u16*)out)[idx] = f2bf(v);
            }
        }
    }
}

// ---------------- split-K reduce: out = f(sum_z part[z]) --------------------
template <int TAG>
__global__ __launch_bounds__(256) void reduce_kernel(const float* __restrict__ part,
                                                     int nsplit, size_t MN,
                                                     const float* __restrict__ bias, int N,
                                                     const u16* __restrict__ res1,
                                                     const u16* __restrict__ res2,
                                                     void* __restrict__ out,
                                                     int relu, int final_store,
                                                     const int* __restrict__ flag) {
    const size_t i0 = ((size_t)blockIdx.x * 256 + threadIdx.x) * 4;
    float4 s = *(const float4*)&part[i0];
    for (int z = 1; z < nsplit; z++) {
        float4 p = *(const float4*)&part[(size_t)z * MN + i0];
        s.x += p.x; s.y += p.y; s.z += p.z; s.w += p.w;
    }
    const int col = (int)(i0 & (size_t)(N - 1));
    float v[4] = {s.x, s.y, s.z, s.w};
#pragma unroll
    for (int j = 0; j < 4; j++) {
        v[j] += bias[col + j];
        if (relu) v[j] = fmaxf(v[j], 0.f);
    }
    if (res1) {
        u16 r[4]; *(uint2*)r = *(const uint2*)&res1[i0];
#pragma unroll
        for (int j = 0; j < 4; j++) v[j] += bf2f(r[j]);
    }
    if (res2) {
        u16 r[4]; *(uint2*)r = *(const uint2*)&res2[i0];
#pragma unroll
        for (int j = 0; j < 4; j++) v[j] += bf2f(r[j]);
    }
    if (final_store && (*flag == 0)) {
        *(float4*)&((float*)out)[i0] = (float4){v[0], v[1], v[2], v[3]};
    } else {
        u16 o[4];
#pragma unroll
        for (int j = 0; j < 4; j++) o[j] = f2bf(v[j]);
        *(uint2*)&((u16*)out)[i0] = *(uint2*)o;
    }
}

// ---------------- flash attention v7: key-split chunks ----------------------
// Un-maxed online softmax (p = exp2(s*Cs)) means partials combine ADDITIVELY:
// O = sum O_c, l = sum l_c. Split each q-block's key range into chunks of <=8
// K-steps so all 2560 blocks are near-uniform (fixes the causal-imbalance
// occupancy collapse: 19% observed at 1024 variable-length blocks). qb 0..7
// (single chunk) normalize+store directly; qb>=8 write f32 partials, combined
// by flash_combine_kernel. Per-step compute path identical to verified v6.
template <int SPLIT>
__global__ __launch_bounds__(256) void flash_kernel(const u16* __restrict__ Q,
                                                    const u16* __restrict__ Kg,
                                                    const u16* __restrict__ VtG,
                                                    u16* __restrict__ O,
                                                    float* __restrict__ pO,
                                                    float* __restrict__ pL) {
    const int tid = threadIdx.x;
    const int wave = tid >> 6, lane = tid & 63;
    int qb, ch;
    if (SPLIT) {
        const int i = blockIdx.x;                  // long blocks first
        if (i < 32)      { qb = 31 - (i >> 2); ch = i & 3; }
        else if (i < 56) { const int j = i - 32; qb = 23 - j / 3; ch = j % 3; }
        else if (i < 72) { const int j = i - 56; qb = 15 - (j >> 1); ch = j & 1; }
        else             { qb = 7 - (i - 72); ch = 0; }
    } else {
        qb = 31 - blockIdx.x; ch = 0;
    }
    const int bh = blockIdx.y;
    const int t0 = qb * 64;
    const int steps = qb + 1;
    const int ktbeg = SPLIT ? ch * 8 : 0;
    const int ktend = SPLIT ? (steps < ktbeg + 8 ? steps : ktbeg + 8) : steps;
    const size_t base = ((size_t)(bh >> 4) * 2048) * 1024 + (size_t)(bh & 15) * 64;
    const size_t basev = (size_t)bh * 64 * 2048;

    __shared__ __align__(16) u16 Ks[2][64 * 64];
    __shared__ __align__(16) u16 Vt[2][64 * 64];
#if !__has_builtin(__builtin_amdgcn_mfma_f32_16x16x16bf16_1k)
    __shared__ __align__(16) u16 Ps[4][16 * 72];
#endif

    const int l15 = lane & 15, quad = lane >> 4;
    const int rmin = t0 + wave * 16;           // this wave's 16 q-rows

    // Q fragments (B-operand): lane holds Q[qrow=l15][d = st*32 + quad*8 ..+7]
    short8 qf[2];
    {
        const u16* qp = Q + base + (size_t)(rmin + l15) * 1024 + quad * 8;
        qf[0] = *(const short8*)qp;
        qf[1] = *(const short8*)(qp + 32);
    }

    const int slr = lane >> 3;                 // 0..7
    const int sc8 = (lane & 7) ^ slr;          // swizzled source col-chunk
    const int rb = wave * 16;                  // 4 waves x 16 rows = 64-row tile

    auto stage = [&](int kt, int bufi) {
        gl_lds16(Kg + base + (size_t)(kt * 64 + rb + slr) * 1024 + sc8 * 8,
                 &Ks[bufi][rb * 64 + lane * 8]);
        gl_lds16(Kg + base + (size_t)(kt * 64 + rb + 8 + slr) * 1024 + sc8 * 8,
                 &Ks[bufi][(rb + 8) * 64 + lane * 8]);
        gl_lds16(VtG + basev + (size_t)(rb + slr) * 2048 + kt * 64 + sc8 * 8,
                 &Vt[bufi][rb * 64 + lane * 8]);
        gl_lds16(VtG + basev + (size_t)(rb + 8 + slr) * 2048 + kt * 64 + sc8 * 8,
                 &Vt[bufi][(rb + 8) * 64 + lane * 8]);
    };

    float l_part = 0.f;
    f32x4 oacc[4];
#pragma unroll
    for (int jt = 0; jt < 4; jt++) oacc[jt] = (f32x4){0.f, 0.f, 0.f, 0.f};

    const float Cs = 0.125f * 1.44269504f;     // scale * log2(e)

    stage(ktbeg, 0);
    __syncthreads();

    for (int kt = ktbeg; kt < ktend; kt++) {
        const int cur = kt & 1;
        if (kt + 1 < ktend) stage(kt + 1, cur ^ 1);   // prefetch overlaps compute

        // K fragments (A-operand): lane holds K[key=j*16+l15][d chunk st*4+quad]
        short8 kf[2][4];
#pragma unroll
        for (int st = 0; st < 2; st++)
#pragma unroll
            for (int j = 0; j < 4; j++)
                kf[st][j] = *(const short8*)&Ks[cur][(j * 16 + l15) * 64 +
                                                     (((st * 4 + quad) ^ (l15 & 7)) * 8)];
#if __has_builtin(__builtin_amdgcn_mfma_f32_16x16x16bf16_1k)
        // V b64 fragments for 16x16x16 PV: lane holds V[key=j*16+quad*4+jj][d=jt*16+l15]
        short4v vf[4][4];
#pragma unroll
        for (int j = 0; j < 4; j++) {
            int k8 = j * 2 + (quad >> 1);      // data key-chunk
#pragma unroll
            for (int jt = 0; jt < 4; jt++) {
                int d = jt * 16 + l15;
                vf[j][jt] = *(const short4v*)&Vt[cur][d * 64 + ((k8 ^ (d & 7)) * 8) +
                                                      (quad & 1) * 4];
            }
        }
#else
        short8 vf[2][4];
#pragma unroll
        for (int st = 0; st < 2; st++)
#pragma unroll
            for (int jt = 0; jt < 4; jt++) {
                int d = jt * 16 + l15;
                vf[st][jt] = *(const short8*)&Vt[cur][d * 64 + (((st * 4 + quad) ^ (d & 7)) * 8)];
            }
#endif

        // S^T = K Q^T : lane gets qrow=l15, keys j*16+quad*4+r
        f32x4 s[4];
#pragma unroll
        for (int j = 0; j < 4; j++) s[j] = (f32x4){0.f, 0.f, 0.f, 0.f};
#pragma unroll
        for (int st = 0; st < 2; st++)
#pragma unroll
            for (int j = 0; j < 4; j++)
                s[j] = __builtin_amdgcn_mfma_f32_16x16x32_bf16(kf[st][j], qf[st], s[j], 0, 0, 0);

        const int qrow = rmin + l15;
        const bool needmask = (kt * 64 + 63 > rmin);
        float lp = l_part;
        short4v pj[4];
#pragma unroll
        for (int j = 0; j < 4; j++) {
            union { short4v v; u16 u[4]; } pk;
#pragma unroll
            for (int r = 0; r < 4; r++) {
                float p = __builtin_amdgcn_exp2f(s[j][r] * Cs);
                int key = kt * 64 + j * 16 + quad * 4 + r;
                if (needmask && key > qrow) p = 0.f;
                lp += p;
                pk.u[r] = f2bf_fast(p);
            }
            pj[j] = pk.v;
        }
        l_part = lp;

#if __has_builtin(__builtin_amdgcn_mfma_f32_16x16x16bf16_1k)
        // O += P V, P straight from registers (A-frag match)
#pragma unroll
        for (int jt = 0; jt < 4; jt++)
#pragma unroll
            for (int j = 0; j < 4; j++)
                oacc[jt] = __builtin_amdgcn_mfma_f32_16x16x16bf16_1k(pj[j], vf[j][jt],
                                                                     oacc[jt], 0, 0, 0);
#else
        // fallback: b64 P-writes to padded LDS, b128 reads as 16x16x32 A-frag
        u16* Pw = Ps[wave];
#pragma unroll
        for (int j = 0; j < 4; j++)
            *(short4v*)&Pw[l15 * 72 + j * 16 + quad * 4] = pj[j];
#pragma unroll
        for (int st = 0; st < 2; st++) {
            short8 pf = *(const short8*)&Pw[l15 * 72 + st * 32 + quad * 8];
#pragma unroll
            for (int jt = 0; jt < 4; jt++)
                oacc[jt] = __builtin_amdgcn_mfma_f32_16x16x32_bf16(pf, vf[st][jt],
                                                                  oacc[jt], 0, 0, 0);
        }
#endif
        __syncthreads();
    }

    // l reduction: l lives per qrow=l15; reduce across quads
    float lf = l_part;
    lf += __shfl_xor(lf, 16, 64);
    lf += __shfl_xor(lf, 32, 64);

    if (SPLIT && steps > 8) {
        // multi-chunk q-block: write un-normalized f32 partials
        const size_t ib = ((size_t)bh * 24 + (qb - 8)) * 4 + ch;
        float* po = pO + ib * 4096;
#pragma unroll
        for (int jt = 0; jt < 4; jt++)
#pragma unroll
            for (int r = 0; r < 4; r++)
                po[(wave * 16 + quad * 4 + r) * 64 + jt * 16 + l15] = oacc[jt][r];
        if (quad == 0) pL[ib * 64 + wave * 16 + l15] = lf;
        return;
    }

    // single-chunk: normalize and store bf16
    {
        float inv[4];
#pragma unroll
        for (int r = 0; r < 4; r++) inv[r] = 1.f / __shfl(lf, quad * 4 + r, 64);
#pragma unroll
        for (int jt = 0; jt < 4; jt++) {
            int d = jt * 16 + l15;
#pragma unroll
            for (int r = 0; r < 4; r++) {
                int t = rmin + quad * 4 + r;
                O[base + (size_t)t * 1024 + d] = f2bf(oacc[jt][r] * inv[r]);
            }
        }
    }
}

// ---------------- flash combine: O = (sum_c O_c) / (sum_c l_c) --------------
__global__ __launch_bounds__(256) void flash_combine_kernel(const float* __restrict__ pO,
                                                            const float* __restrict__ pL,
                                                            u16* __restrict__ O) {
    const int qj = blockIdx.x;                 // 0..23 -> qb = qj + 8
    const int bh = blockIdx.y;
    const int qb = qj + 8;
    const int nch = (qb >> 3) + 1;             // 2, 3 or 4 chunks
    const int tid = threadIdx.x;
    const int row = tid >> 2;                  // 0..63
    const int d0 = (tid & 3) * 16;
    const size_t ib = ((size_t)bh * 24 + qj) * 4;

    float acc[16];
#pragma unroll
    for (int k = 0; k < 16; k++) acc[k] = 0.f;
    float lsum = 0.f;
    for (int c = 0; c < nch; c++) {
        const float* po = pO + (ib + c) * 4096 + row * 64 + d0;
#pragma unroll
        for (int v = 0; v < 4; v++) {
            float4 f = *(const float4*)&po[v * 4];
            acc[v * 4 + 0] += f.x; acc[v * 4 + 1] += f.y;
            acc[v * 4 + 2] += f.z; acc[v * 4 + 3] += f.w;
        }
        lsum += pL[(ib + c) * 64 + row];
    }
    const float inv = 1.f / lsum;
    u16 o[16];
#pragma unroll
    for (int k = 0; k < 16; k++) o[k] = f2bf(acc[k] * inv);
    const size_t base = ((size_t)(bh >> 4) * 2048) * 1024 + (size_t)(bh & 15) * 64;
    const int t = qb * 64 + row;
    u16* op = &O[base + (size_t)t * 1024 + d0];
    *(uint4*)op = ((uint4*)o)[0];
    *(uint4*)(op + 8) = ((uint4*)o)[1];
}

extern "C" void kernel_launch(void* const* d_in, const int* in_sizes, int n_in,
                              void* d_out, int out_size, void* d_ws, size_t ws_size,
                              hipStream_t stream) {
    (void)in_sizes; (void)n_in; (void)out_size;
    const void* x   = d_in[0];
    // d_in[1] = attn_mask (int32, pure causal) -- implemented directly
    const void* Wq  = d_in[2];  const void* bq  = d_in[3];
    const void* Wk  = d_in[4];  const void* bk  = d_in[5];
    const void* Wv  = d_in[6];  const void* bv  = d_in[7];
    const void* Wo  = d_in[8];  const void* bo  = d_in[9];
    const void* g1  = d_in[10]; const void* be1 = d_in[11];
    const void* g2  = d_in[12]; const void* be2 = d_in[13];
    const void* W1  = d_in[14]; const void* bf1 = d_in[15];
    const void* W2  = d_in[16]; const void* bf2 = d_in[17];
    const void* Wd  = d_in[18]; const void* bd  = d_in[19];
    const void* Wu  = d_in[20]; const void* bu  = d_in[21];

    uint8_t* w8 = (uint8_t*)d_ws;
    int* flag = (int*)w8;                    // 64 B header
    float* pf = (float*)(w8 + 64);           // f32 param pool
    u16* wsb = (u16*)(w8 + 64 + 65536);      // bf16 arena

    const size_t M1 = 1024ull * 1024ull;
    u16* WqT = wsb;                          // Wq/Wk/Wv transposed, contiguous 3072xK
    u16* WkT = wsb + 1 * M1;
    u16* WvT = wsb + 2 * M1;
    u16* WoT = wsb + 3 * M1;
    u16* W1T = wsb + 4 * M1;                 // 4M
    u16* W2T = wsb + 8 * M1;                 // 4M
    u16* WdT = wsb + 12 * M1;                // 64K
    u16* WuT = wsb + 12 * M1 + 65536;        // 64K
    u16* S0  = wsb + 12 * M1 + 131072;
    u16* Areg = S0;                          // xb
    u16* Breg = S0 + 4 * M1;                 // xn -> attn
    u16* ff1  = S0;                          // 16M spans Areg+Breg+8M fresh
    u16* Creg = S0 + 16 * M1;                // q -> xn2 -> bot
    u16* Dreg = S0 + 20 * M1;                // k -> x1
    u16* Ereg = S0 + 24 * M1;                // VtG -> hh
    u16* xb = Areg;
    u16* xn = Breg; u16* attn = Breg;
    u16* q = Creg;  u16* xn2 = Creg;  u16* bot = Creg;
    u16* kk_ = Dreg; u16* x1 = Dreg;
    u16* VtG = Ereg; u16* hh = Ereg;

    // f32 partial buffer after the bf16 arena
    // (time-shared: flash partials [48MB O + 1MB l] -> adapter split-K)
    const size_t arena_bytes = (size_t)(64 + 65536) + (40 * M1 + 131072) * 2;
    float* partf = (float*)(w8 + ((arena_bytes + 255) & ~(size_t)255));
    const size_t need = ((arena_bytes + 255) & ~(size_t)255) + 4ull * 4 * M1 * 4;
    const bool sk = ws_size >= need;
    float* flL = partf + 14 * M1;            // flash l partials at +56MB

    float* bqkv_f = pf + 0;    // bq,bk,bv contiguous (3072)
    float* bo_f  = pf + 3072;
    float* bf1_f = pf + 4096;  float* bf2_f = pf + 8192;
    float* bd_f  = pf + 9216;  float* bu_f  = pf + 9280;
    float* g1_f  = pf + 10304; float* be1_f = pf + 11328;
    float* g2_f  = pf + 12352; float* be2_f = pf + 13376;

    detect_kernel<<<1, 256, 0, stream>>>((const unsigned*)x, flag);

    ParamCvt pc;
    const void* srcs[12] = {bq, bk, bv, bo, bf1, bf2, bd, bu, g1, be1, g2, be2};
    int offs[12] = {0, 1024, 2048, 3072, 4096, 8192, 9216, 9280, 10304, 11328, 12352, 13376};
    int ns[12]   = {1024, 1024, 1024, 1024, 4096, 1024, 64, 1024, 1024, 1024, 1024, 1024};
    for (int i = 0; i < 12; i++) { pc.src[i] = srcs[i]; pc.off[i] = offs[i]; pc.n[i] = ns[i]; }
    param_cvt_kernel<<<12, 256, 0, stream>>>(pc, pf, flag);

    cvt_x_kernel<<<4096, 256, 0, stream>>>(x, xb, flag);

    TAll ta;
    const void* tsrc[8] = {Wq, Wk, Wv, Wo, W1, W2, Wd, Wu};
    u16* tdst[8] = {WqT, WkT, WvT, WoT, W1T, W2T, WdT, WuT};
    int tR[8] = {1024, 1024, 1024, 1024, 1024, 4096, 1024, 64};
    int tC[8] = {1024, 1024, 1024, 1024, 4096, 1024, 64, 1024};
    int acc_off = 0;
    for (int i = 0; i < 8; i++) {
        ta.src[i] = tsrc[i]; ta.dst[i] = tdst[i];
        ta.R[i] = tR[i]; ta.C[i] = tC[i];
        ta.off[i] = acc_off;
        acc_off += (tR[i] >> 5) * (tC[i] >> 5);
    }
    transpose_all_kernel<<<acc_off, 256, 0, stream>>>(ta, flag);

    ln_kernel<<<4096, 256, 0, stream>>>(xb, g1_f, be1_f, xn);
    // TAG 0: fused QKV (N=3072, V written transposed per-head into VtG)
    // 768 blocks -> 2 blocks/CU residency + backfill
    gemm128_kernel<0><<<dim3(24, 32), 512, 0, stream>>>(xn, WqT, bqkv_f, nullptr, nullptr,
                                                        q, kk_, VtG, 4096, 3072, 1024, 0, 2, flag);
    if (sk) {
        flash_kernel<1><<<dim3(80, 32), 256, 0, stream>>>(q, kk_, VtG, attn, partf, flL);
        flash_combine_kernel<<<dim3(24, 32), 256, 0, stream>>>(partf, flL, attn);
    } else {
        flash_kernel<0><<<dim3(32, 32), 256, 0, stream>>>(q, kk_, VtG, attn, nullptr, nullptr);
    }
    // TAG 1: Wo projection + bias + residual, direct (no split-K)
    gemm128_kernel<1><<<dim3(8, 32), 512, 0, stream>>>(attn, WoT, bo_f, xb, nullptr,
                                                       x1, nullptr, nullptr, 4096, 1024, 1024, 0, 0, flag);
    ln_kernel<<<4096, 256, 0, stream>>>(x1, g2_f, be2_f, xn2);
    // TAG 2: FFN1 (relu), 1024 blocks -> 2 blocks/CU residency
    gemm128_kernel<2><<<dim3(32, 32), 512, 0, stream>>>(xn2, W1T, bf1_f, nullptr, nullptr,
                                                        ff1, nullptr, nullptr, 4096, 4096, 1024, 1, 0, flag);
    // TAG 3: FFN2 direct, nt=64 (no split-K)
    gemm128_kernel<3><<<dim3(8, 32), 512, 0, stream>>>(ff1, W2T, bf2_f, nullptr, nullptr,
                                                       hh, nullptr, nullptr, 4096, 1024, 4096, 0, 0, flag);
    // TAG 4: adapter down (relu, split-K 8) -- N=64, stays on legacy kernel
    if (sk) {
        gemm_bt_kernel<4><<<dim3(1, 32, 8), 256, 0, stream>>>(hh, WdT, nullptr, nullptr, nullptr,
                                                              partf, nullptr, nullptr, 4096, 64, 1024, 1, 3, flag);
        reduce_kernel<4><<<256, 256, 0, stream>>>(partf, 8, 256 * 1024, bd_f, 64, nullptr, nullptr,
                                                  bot, 1, 0, flag);
    } else {
        gemm_bt_kernel<4><<<dim3(1, 32), 256, 0, stream>>>(hh, WdT, bd_f, nullptr, nullptr,
                                                           bot, nullptr, nullptr, 4096, 64, 1024, 1, 0, flag);
    }
    // TAG 5: adapter up + residuals (final store) -- K=64, stays on legacy kernel
    gemm_bt_kernel<5><<<dim3(8, 32), 256, 0, stream>>>(bot, WuT, bu_f, hh, x1,
                                                       d_out, nullptr, nullptr, 4096, 1024, 64, 0, 1, flag);
}